// Round 15
// baseline (230.651 us; speedup 1.0000x reference)
//
#include <hip/hip_runtime.h>

#define N_NODES 10000
#define N_EDGES 100000
#define F_NODE 128
#define HEADS 8
#define HC 1024
#define NCOLS2 2432  // xg(1024) v(1024) skip(128) qwe(128) du(8) sv(8) pad(112)
#define NB2 (NCOLS2 / 128)   // 19
#define SLOT_CAP 48
#define XV_STRIDE 2048       // bytes: [x fp8 128][sv f32 32][pad][v fp8 @1024]

typedef __attribute__((ext_vector_type(8))) short bf16x8;
typedef __attribute__((ext_vector_type(4))) float f32x4;
typedef __attribute__((ext_vector_type(2))) float f32x2;

__device__ __forceinline__ void atomAddF(float* p, float v) {
    unsafeAtomicAdd(p, v);
}
__device__ __forceinline__ unsigned short f2bf(float f) {
    union { float f; unsigned u; } c; c.f = f;
    unsigned u = c.u + 0x7fffu + ((c.u >> 16) & 1u);  // RNE
    return (unsigned short)(u >> 16);
}
__device__ __forceinline__ float bLo(unsigned x) {
    union { unsigned u; float f; } c; c.u = x << 16; return c.f;
}
__device__ __forceinline__ float bHi(unsigned x) {
    union { unsigned u; float f; } c; c.u = x & 0xffff0000u; return c.f;
}
__device__ __forceinline__ float bf2f(unsigned short u) {
    union { unsigned u; float f; } c; c.u = ((unsigned)u) << 16; return c.f;
}
__device__ __forceinline__ unsigned pk4fp8(unsigned a, unsigned b) {
    int w = __builtin_amdgcn_cvt_pk_fp8_f32(bLo(a), bHi(a), 0, false);
    w = __builtin_amdgcn_cvt_pk_fp8_f32(bLo(b), bHi(b), w, true);
    return (unsigned)w;
}
__device__ __forceinline__ float dot128(const float* __restrict__ a,
                                        const float* __restrict__ b) {
    const float4* a4 = (const float4*)a;
    const float4* b4 = (const float4*)b;
    float s = 0.f;
    #pragma unroll
    for (int c = 0; c < 32; ++c) {
        float4 x4 = a4[c], y4 = b4[c];
        s += x4.x * y4.x + x4.y * y4.y + x4.z * y4.z + x4.w * y4.w;
    }
    return s;
}

// ================= fused prep: conv + edge-scatter + W build =================
#define PREP_A 1250
#define PREP_B (PREP_A + NCOLS2 / 2)       // 2466
#define PREP_C (PREP_B + 10)               // 2476
#define PREP_D (PREP_C + 64)               // 2540
__global__ __launch_bounds__(256) void prep_all(
    const float* __restrict__ x, unsigned short* __restrict__ xb,
    unsigned char* __restrict__ xv, const int* __restrict__ ei,
    int* __restrict__ cnt, int2* __restrict__ slots,
    const float* __restrict__ Wq, const float* __restrict__ Wk,
    const float* __restrict__ Wv, const float* __restrict__ Wskip,
    const float* __restrict__ We, const float* __restrict__ bq,
    const float* __restrict__ bk, const float* __restrict__ bv,
    const float* __restrict__ bskip, unsigned short* __restrict__ wt,
    float* __restrict__ bias, unsigned short* __restrict__ w2t) {
    int tid = threadIdx.x;
    if (blockIdx.x < PREP_A) {
        int i = blockIdx.x * 256 + tid;
        float4 f = ((const float4*)x)[i];
        ushort4 o;
        o.x = f2bf(f.x); o.y = f2bf(f.y); o.z = f2bf(f.z); o.w = f2bf(f.w);
        ((ushort4*)xb)[i] = o;
        int w = __builtin_amdgcn_cvt_pk_fp8_f32(f.x, f.y, 0, false);
        w = __builtin_amdgcn_cvt_pk_fp8_f32(f.z, f.w, w, true);
        ((unsigned*)xv)[((i >> 5) << 9) + (i & 31)] = (unsigned)w;
        if (i < N_EDGES) {
            int src = ei[i];
            int dst = ei[N_EDGES + i];
            int pos = atomicAdd(&cnt[dst], 1);
            if (pos < SLOT_CAP) slots[(size_t)dst * SLOT_CAP + pos] = make_int2(src, i);
        }
    } else if (blockIdx.x < PREP_B) {
        __shared__ float wesh[2][128];
        int bi = blockIdx.x - PREP_A;
        int cid = tid >> 7, d = tid & 127;
        int n = 2 * bi + cid;
        float val;
        if (n < 1024) {           // G_h[d,f2] = sum_c Wq[d,hc] Wk[f2,hc]
            int h = n >> 7, f2 = n & 127;
            wesh[cid][d] = Wk[(size_t)f2 * HC + h * 128 + d];
            __syncthreads();
            val = dot128(Wq + (size_t)d * HC + h * 128, wesh[cid]);
        } else if (n < 2048) {
            val = Wv[(size_t)d * HC + (n - 1024)];
        } else if (n < 2176) {
            val = Wskip[(size_t)d * 128 + (n - 2048)];
        } else if (n < 2304) {
            int hf = n - 2176, h = hf >> 4, f = hf & 15;
            wesh[cid][d] = We[(size_t)f * HC + h * 128 + d];
            __syncthreads();
            val = dot128(Wq + (size_t)d * HC + h * 128, wesh[cid]);
        } else if (n < 2312) {    // du col: Wq_h . bk_h
            int h = n - 2304;
            wesh[cid][d] = bk[h * 128 + d];
            __syncthreads();
            val = dot128(Wq + (size_t)d * HC + h * 128, wesh[cid]);
        } else if (n < 2320) {    // sv col: Wk_h . bq_h
            int h = n - 2312;
            wesh[cid][d] = bq[h * 128 + d];
            __syncthreads();
            val = dot128(Wk + (size_t)d * HC + h * 128, wesh[cid]);
        } else {
            val = 0.f;
        }
        wt[(size_t)n * 128 + d] = f2bf(val);
    } else if (blockIdx.x < PREP_C) {
        int n = (blockIdx.x - PREP_B) * 256 + tid;
        if (n >= NCOLS2) return;
        float val;
        if (n < 1024) val = 0.f;
        else if (n < 2048) val = bv[n - 1024];
        else if (n < 2176) val = bskip[n - 2048];
        else if (n < 2304) {
            int hf = n - 2176, h = hf >> 4, f = hf & 15;
            float s = 0.f;
            for (int c = 0; c < 128; ++c)
                s += bq[h * 128 + c] * We[(size_t)f * HC + h * 128 + c];
            val = s;
        } else if (n < 2312) {    // c_h = bq_h . bk_h
            int h = n - 2304;
            float s = 0.f;
            for (int c = 0; c < 128; ++c) s += bq[h * 128 + c] * bk[h * 128 + c];
            val = s;
        } else val = 0.f;
        bias[n] = val;
    } else {
        int c = (blockIdx.x - PREP_C) * 2 + (tid >> 7);
        int d = tid & 127;
        int h = d >> 4, f = d & 15;
        w2t[(size_t)c * 128 + d] = f2bf(We[(size_t)f * HC + h * 128 + c] * 0.125f);
    }
}

// ---- MFMA GEMM: [10000,128]bf16 x [128,2432]bf16, LDS-staged ----
__global__ __launch_bounds__(256) void gemm_mfma(
    const unsigned short* __restrict__ xb, const unsigned short* __restrict__ wt,
    const float* __restrict__ bias, unsigned char* __restrict__ xgf8,
    unsigned char* __restrict__ xv, unsigned short* __restrict__ sqb,
    float* __restrict__ du) {
    __shared__ unsigned short lds[18432];
    unsigned short (*As)[72] = (unsigned short(*)[72])lds;
    unsigned short (*Bs)[72] = (unsigned short(*)[72])(lds + 9216);
    int tid = threadIdx.x;
    int n0 = blockIdx.x * 128, m0 = blockIdx.y * 128;
    int w = tid >> 6, lane = tid & 63;
    int wm = (w >> 1) * 64, wn = (w & 1) * 64;
    int quad = lane >> 4, l16 = lane & 15;
    f32x4 acc[4][4];
    #pragma unroll
    for (int i = 0; i < 4; ++i)
        #pragma unroll
        for (int j = 0; j < 4; ++j) acc[i][j] = (f32x4){0.f, 0.f, 0.f, 0.f};

    for (int ko = 0; ko < 128; ko += 64) {
        #pragma unroll
        for (int tI = 0; tI < 4; ++tI) {
            int cId = tid + tI * 256;
            int r = cId >> 3, c8 = (cId & 7) << 3;
            int gr = m0 + r;
            uint4 av = make_uint4(0u, 0u, 0u, 0u);
            if (gr < N_NODES)
                av = *(const uint4*)(xb + (size_t)gr * 128 + ko + c8);
            *(uint4*)(&As[r][c8]) = av;
            *(uint4*)(&Bs[r][c8]) =
                *(const uint4*)(wt + (size_t)(n0 + r) * 128 + ko + c8);
        }
        __syncthreads();
        #pragma unroll
        for (int ks = 0; ks < 64; ks += 32) {
            bf16x8 a[4], b[4];
            #pragma unroll
            for (int mt = 0; mt < 4; ++mt)
                a[mt] = *(const bf16x8*)&As[wm + mt * 16 + l16][ks + quad * 8];
            #pragma unroll
            for (int nt = 0; nt < 4; ++nt)
                b[nt] = *(const bf16x8*)&Bs[wn + nt * 16 + l16][ks + quad * 8];
            #pragma unroll
            for (int mt = 0; mt < 4; ++mt)
                #pragma unroll
                for (int nt = 0; nt < 4; ++nt)
                    acc[mt][nt] = __builtin_amdgcn_mfma_f32_16x16x32_bf16(
                        a[mt], b[nt], acc[mt][nt], 0, 0, 0);
        }
        __syncthreads();
    }
    int nt0 = n0 >> 7;  // 0..7 xg, 8..15 v, 16/17 sq, 18 du/sv
    if (nt0 >= 16) {
        #pragma unroll
        for (int mt = 0; mt < 4; ++mt)
            #pragma unroll
            for (int r = 0; r < 4; ++r) {
                int row = m0 + wm + mt * 16 + quad * 4 + r;
                if (row >= N_NODES) continue;
                #pragma unroll
                for (int nt = 0; nt < 4; ++nt) {
                    int col = n0 + wn + nt * 16 + l16;
                    float val = acc[mt][nt][r] + bias[col];
                    if (col < 2304) {
                        sqb[(size_t)row * 256 + (col - 2048)] = f2bf(val);
                    } else if (col < 2312) {
                        du[(size_t)row * 8 + (col - 2304)] = val;
                    } else if (col < 2320) {
                        *(float*)(xv + (size_t)row * XV_STRIDE + 128 +
                                  (col - 2312) * 4) = val;
                    }
                }
            }
    } else {
        unsigned short* wst = lds + w * 4608;
        #pragma unroll
        for (int mt = 0; mt < 4; ++mt)
            #pragma unroll
            for (int r = 0; r < 4; ++r) {
                int rl = mt * 16 + quad * 4 + r;
                #pragma unroll
                for (int nt = 0; nt < 4; ++nt) {
                    int cl = nt * 16 + l16;
                    wst[rl * 72 + cl] = f2bf(acc[mt][nt][r] + bias[n0 + wn + cl]);
                }
            }
        int colbase = (n0 & 1023) + wn;
        #pragma unroll
        for (int p = 0; p < 4; ++p) {
            int rl = p * 16 + (lane >> 2);
            int row = m0 + wm + rl;
            if (row < N_NODES) {
                const uint4* sp = (const uint4*)(wst + rl * 72 + (lane & 3) * 16);
                uint4 u0 = sp[0], u1 = sp[1];
                uint4 o;
                o.x = pk4fp8(u0.x, u0.y);
                o.y = pk4fp8(u0.z, u0.w);
                o.z = pk4fp8(u1.x, u1.y);
                o.w = pk4fp8(u1.z, u1.w);
                if (nt0 < 8) {
                    *(uint4*)(xgf8 + (size_t)row * 1024 + colbase +
                              (lane & 3) * 16) = o;
                } else {
                    *(uint4*)(xv + (size_t)row * XV_STRIDE + 1024 + colbase +
                              (lane & 3) * 16) = o;
                }
            }
        }
    }
}

// -------- node attention: TWO WAVES PER NODE, slot-broadcast + 4-edge unroll
// Slot list loaded once (lane l holds slot l); src/e via dynamic __shfl --
// removes the slot load from the per-edge dependent chain.
__global__ __launch_bounds__(256) void node_kernel(
    const unsigned char* __restrict__ xgf8, const unsigned char* __restrict__ xv,
    const unsigned short* __restrict__ sqb, const float* __restrict__ ea,
    const float* __restrict__ du, const int2* __restrict__ slots,
    const int* __restrict__ cnt, unsigned short* __restrict__ ttb,
    float* __restrict__ hsum) {
    __shared__ float lva[2][16][64];   // [ns][i][lane] -> conflict-free
    __shared__ float lst[2][3][64];    // s, t0, t1
    int t = threadIdx.x;
    int w = t >> 6, lane = t & 63;
    int ns = w >> 1;          // node slot in block (0/1)
    int half = w & 1;
    int lh = lane & 7, h = lane >> 3;
    const float scale = 0.08838834764831845f;  // 1/sqrt(128)
    int n = blockIdx.x * 2 + ns;   // grid = 5000 exactly

    // whole slot list into registers: lane l holds slot l
    int slx = 0, sle = 0;
    if (lane < SLOT_CAP) {
        int2 s0 = slots[(size_t)n * SLOT_CAP + lane];
        slx = s0.x; sle = s0.y;
    }

    uint4 gq = *(const uint4*)(xgf8 + (size_t)n * 1024 + 16 * lane);
    float gf[16];
    {
        f32x2 p;
        p = __builtin_amdgcn_cvt_pk_f32_fp8(gq.x, false); gf[0] = p.x; gf[1] = p.y;
        p = __builtin_amdgcn_cvt_pk_f32_fp8(gq.x, true);  gf[2] = p.x; gf[3] = p.y;
        p = __builtin_amdgcn_cvt_pk_f32_fp8(gq.y, false); gf[4] = p.x; gf[5] = p.y;
        p = __builtin_amdgcn_cvt_pk_f32_fp8(gq.y, true);  gf[6] = p.x; gf[7] = p.y;
        p = __builtin_amdgcn_cvt_pk_f32_fp8(gq.z, false); gf[8] = p.x; gf[9] = p.y;
        p = __builtin_amdgcn_cvt_pk_f32_fp8(gq.z, true);  gf[10] = p.x; gf[11] = p.y;
        p = __builtin_amdgcn_cvt_pk_f32_fp8(gq.w, false); gf[12] = p.x; gf[13] = p.y;
        p = __builtin_amdgcn_cvt_pk_f32_fp8(gq.w, true);  gf[14] = p.x; gf[15] = p.y;
    }
    ushort2 qwu = *(const ushort2*)(sqb + (size_t)n * 256 + 128 + h * 16 + 2 * lh);
    float qwx = bf2f(qwu.x), qwy = bf2f(qwu.y);
    float du_r = du[(size_t)n * 8 + h];

    int cn = cnt[n];
    cn = (cn > SLOT_CAP) ? SLOT_CAP : cn;
    int mid = (cn + 1) >> 1;
    int begin = half ? mid : 0;
    int end = half ? cn : mid;
    float va[16];
    #pragma unroll
    for (int i = 0; i < 16; ++i) va[i] = 0.f;
    float s_reg = 0.f, t0 = 0.f, t1 = 0.f;

    for (int ii = begin; ii < end; ii += 4) {
        int srcj[4], ej[4];
        bool valid[4];
        #pragma unroll
        for (int j = 0; j < 4; ++j) {
            int id = ii + j;
            valid[j] = (id < end);
            id = valid[j] ? id : end - 1;
            srcj[j] = __shfl(slx, id);
            ej[j] = __shfl(sle, id);
        }
        uint4 xg4[4], vg4[4];
        float2 eav[4];
        float svr[4];
        #pragma unroll
        for (int j = 0; j < 4; ++j) {
            const unsigned char* base = xv + ((size_t)srcj[j] << 11);
            xg4[j] = *(const uint4*)(base + lh * 16);
            vg4[j] = *(const uint4*)(base + 1024 + lane * 16);
            svr[j] = *(const float*)(base + 128 + h * 4);
            eav[j] = *(const float2*)(ea + (size_t)ej[j] * 16 + 2 * lh);
        }
        #pragma unroll
        for (int j = 0; j < 4; ++j) {
            float d = eav[j].x * qwx + eav[j].y * qwy;
            f32x2 p;
            p = __builtin_amdgcn_cvt_pk_f32_fp8(xg4[j].x, false); d += gf[0]*p.x + gf[1]*p.y;
            p = __builtin_amdgcn_cvt_pk_f32_fp8(xg4[j].x, true);  d += gf[2]*p.x + gf[3]*p.y;
            p = __builtin_amdgcn_cvt_pk_f32_fp8(xg4[j].y, false); d += gf[4]*p.x + gf[5]*p.y;
            p = __builtin_amdgcn_cvt_pk_f32_fp8(xg4[j].y, true);  d += gf[6]*p.x + gf[7]*p.y;
            p = __builtin_amdgcn_cvt_pk_f32_fp8(xg4[j].z, false); d += gf[8]*p.x + gf[9]*p.y;
            p = __builtin_amdgcn_cvt_pk_f32_fp8(xg4[j].z, true);  d += gf[10]*p.x + gf[11]*p.y;
            p = __builtin_amdgcn_cvt_pk_f32_fp8(xg4[j].w, false); d += gf[12]*p.x + gf[13]*p.y;
            p = __builtin_amdgcn_cvt_pk_f32_fp8(xg4[j].w, true);  d += gf[14]*p.x + gf[15]*p.y;
            d += __shfl_xor(d, 1); d += __shfl_xor(d, 2); d += __shfl_xor(d, 4);
            float a = __expf((d + du_r + svr[j]) * scale);
            a = valid[j] ? a : 0.f;
            s_reg += a;
            t0 += a * eav[j].x; t1 += a * eav[j].y;
            p = __builtin_amdgcn_cvt_pk_f32_fp8(vg4[j].x, false); va[0] += a*p.x; va[1] += a*p.y;
            p = __builtin_amdgcn_cvt_pk_f32_fp8(vg4[j].x, true);  va[2] += a*p.x; va[3] += a*p.y;
            p = __builtin_amdgcn_cvt_pk_f32_fp8(vg4[j].y, false); va[4] += a*p.x; va[5] += a*p.y;
            p = __builtin_amdgcn_cvt_pk_f32_fp8(vg4[j].y, true);  va[6] += a*p.x; va[7] += a*p.y;
            p = __builtin_amdgcn_cvt_pk_f32_fp8(vg4[j].z, false); va[8] += a*p.x; va[9] += a*p.y;
            p = __builtin_amdgcn_cvt_pk_f32_fp8(vg4[j].z, true);  va[10] += a*p.x; va[11] += a*p.y;
            p = __builtin_amdgcn_cvt_pk_f32_fp8(vg4[j].w, false); va[12] += a*p.x; va[13] += a*p.y;
            p = __builtin_amdgcn_cvt_pk_f32_fp8(vg4[j].w, true);  va[14] += a*p.x; va[15] += a*p.y;
        }
    }
    // merge halves through LDS (conflict-free layout)
    if (half == 0) {
        #pragma unroll
        for (int i = 0; i < 16; ++i) lva[ns][i][lane] = va[i];
        lst[ns][0][lane] = s_reg;
        lst[ns][1][lane] = t0;
        lst[ns][2][lane] = t1;
    }
    __syncthreads();
    if (half == 1) {
        s_reg += lst[ns][0][lane];
        t0 += lst[ns][1][lane];
        t1 += lst[ns][2][lane];
        #pragma unroll
        for (int i = 0; i < 16; ++i) va[i] += lva[ns][i][lane];

        float inv = 1.f / (s_reg + 1e-16f);
        ushort2 tw;
        tw.x = f2bf(t0 * inv);
        tw.y = f2bf(t1 * inv);
        *(ushort2*)(ttb + (size_t)n * 128 + h * 16 + 2 * lh) = tw;
        float sc = inv * 0.125f;
        #pragma unroll
        for (int i = 0; i < 16; ++i) {
            float o = va[i] * sc;
            o += __shfl_xor(o, 8);
            o += __shfl_xor(o, 16);
            o += __shfl_xor(o, 32);
            va[i] = o;
        }
        if (lane < 8) {
            float* hp = hsum + (size_t)n * 128 + lane * 16;
            #pragma unroll
            for (int p2 = 0; p2 < 4; ++p2) {
                float4 h4 = make_float4(va[4 * p2], va[4 * p2 + 1],
                                        va[4 * p2 + 2], va[4 * p2 + 3]);
                ((float4*)hp)[p2] = h4;
            }
        }
    }
}

// -- out GEMM: m-tile 32 (313 blocks), LDS-staged A, epilogue + final -------
__global__ __launch_bounds__(256) void out_gemm(
    const unsigned short* __restrict__ ttb, const unsigned short* __restrict__ w2t,
    const float* __restrict__ hsum, const unsigned short* __restrict__ sqb,
    float* __restrict__ pooled, int* __restrict__ done,
    const float* __restrict__ Wd, const float* __restrict__ bd,
    float* __restrict__ out) {
    __shared__ unsigned short As[32][136];
    __shared__ float pool_sh[128];
    __shared__ int last_sh;
    int tid = threadIdx.x;
    int m0 = blockIdx.x * 32;
    int w = tid >> 6, lane = tid & 63;
    int wm = (w >> 1) * 16, wn = (w & 1) * 64;
    int quad = lane >> 4, l16 = lane & 15;
    if (tid < 128) pool_sh[tid] = 0.f;
    #pragma unroll
    for (int tI = 0; tI < 2; ++tI) {
        int cId = tid + tI * 256;
        int r = cId >> 4, c8 = (cId & 15) << 3;
        int gr = m0 + r;
        uint4 av = make_uint4(0u, 0u, 0u, 0u);
        if (gr < N_NODES)
            av = *(const uint4*)(ttb + (size_t)gr * 128 + c8);
        *(uint4*)(&As[r][c8]) = av;
    }
    __syncthreads();
    f32x4 acc[4];
    #pragma unroll
    for (int j = 0; j < 4; ++j) acc[j] = (f32x4){0.f, 0.f, 0.f, 0.f};

    const unsigned short* bb = w2t + (size_t)(wn + l16) * 128 + quad * 8;
    #pragma unroll
    for (int ks = 0; ks < 128; ks += 32) {
        bf16x8 a = *(const bf16x8*)&As[wm + l16][ks + quad * 8];
        #pragma unroll
        for (int nt = 0; nt < 4; ++nt) {
            bf16x8 b = *(const bf16x8*)(bb + (size_t)nt * 16 * 128 + ks);
            acc[nt] = __builtin_amdgcn_mfma_f32_16x16x32_bf16(a, b, acc[nt], 0, 0, 0);
        }
    }
    float pl[4] = {0.f, 0.f, 0.f, 0.f};
    #pragma unroll
    for (int r = 0; r < 4; ++r) {
        int row = m0 + wm + quad * 4 + r;
        if (row >= N_NODES) continue;
        #pragma unroll
        for (int nt = 0; nt < 4; ++nt) {
            int col = wn + nt * 16 + l16;
            float val = acc[nt][r] + hsum[(size_t)row * 128 + col]
                        + bf2f(sqb[(size_t)row * 256 + col]);
            pl[nt] += fmaxf(val, 0.f);
        }
    }
    #pragma unroll
    for (int nt = 0; nt < 4; ++nt)
        atomicAdd(&pool_sh[wn + nt * 16 + l16], pl[nt]);
    __syncthreads();
    if (tid < 128) atomAddF(&pooled[tid], pool_sh[tid]);
    __threadfence();
    if (tid == 0) last_sh = (atomicAdd(done, 1) == (int)gridDim.x - 1);
    __syncthreads();
    if (last_sh && tid < 64) {
        float p0 = __hip_atomic_load(&pooled[2 * tid], __ATOMIC_RELAXED,
                                     __HIP_MEMORY_SCOPE_AGENT);
        float p1 = __hip_atomic_load(&pooled[2 * tid + 1], __ATOMIC_RELAXED,
                                     __HIP_MEMORY_SCOPE_AGENT);
        float vv = p0 * Wd[2 * tid] + p1 * Wd[2 * tid + 1];
        vv += __shfl_xor(vv, 1);  vv += __shfl_xor(vv, 2);  vv += __shfl_xor(vv, 4);
        vv += __shfl_xor(vv, 8);  vv += __shfl_xor(vv, 16); vv += __shfl_xor(vv, 32);
        if (tid == 0) out[0] = vv + bd[0];
    }
}

extern "C" void kernel_launch(void* const* d_in, const int* in_sizes, int n_in,
                              void* d_out, int out_size, void* d_ws, size_t ws_size,
                              hipStream_t stream) {
    const float* x     = (const float*)d_in[0];
    const float* eattr = (const float*)d_in[1];
    const int*   ei    = (const int*)d_in[2];
    const float* Wq    = (const float*)d_in[3];
    const float* bq    = (const float*)d_in[4];
    const float* Wk    = (const float*)d_in[5];
    const float* bk    = (const float*)d_in[6];
    const float* Wv    = (const float*)d_in[7];
    const float* bv    = (const float*)d_in[8];
    const float* We    = (const float*)d_in[9];
    const float* Wskip = (const float*)d_in[10];
    const float* bskip = (const float*)d_in[11];
    const float* Wd    = (const float*)d_in[12];
    const float* bd    = (const float*)d_in[13];
    float* out = (float*)d_out;

    char* ws = (char*)d_ws;
    unsigned char*  xgf8 = (unsigned char*)(ws + 0);           // 10,240,000
    unsigned char*  xv   = (unsigned char*)(ws + 10240000);    // 20,480,000
    unsigned short* sqb  = (unsigned short*)(ws + 30720000);   //  5,120,000
    float* hsum = (float*)(ws + 35840000);                     //  5,120,000
    unsigned short* xb   = (unsigned short*)(ws + 40960000);   //  2,560,000
    unsigned short* ttb  = xb;  // reuse: xb dead after gemm_mfma
    float* du   = (float*)(ws + 43520000);                     //    320,000
    unsigned short* wt   = (unsigned short*)(ws + 43840000);   //    622,592
    float* bias = (float*)(ws + 44462592);                     //      9,728
    unsigned short* w2t  = (unsigned short*)(ws + 44472320);   //     32,768
    int* cnt    = (int*)(ws + 44505088);                       //     40,000
    float* pooled = (float*)(ws + 44545088);                   //        512
    int* done   = (int*)(ws + 44545600);                       //         16
    int2* slots = (int2*)(ws + 44545616);                      //  3,840,000

    hipMemsetAsync(cnt, 0, 40000 + 512 + 16, stream);

    prep_all<<<PREP_D, 256, 0, stream>>>(
        x, xb, xv, ei, cnt, slots, Wq, Wk, Wv, Wskip, We, bq, bk, bv, bskip,
        wt, bias, w2t);

    gemm_mfma<<<dim3(NB2, (N_NODES + 127) / 128), 256, 0, stream>>>(
        xb, wt, bias, xgf8, xv, sqb, du);

    node_kernel<<<N_NODES / 2, 256, 0, stream>>>(
        xgf8, xv, sqb, eattr, du, slots, cnt, ttb, hsum);

    out_gemm<<<(N_NODES + 31) / 32, 256, 0, stream>>>(
        ttb, w2t, hsum, sqb, pooled, done, Wd, bd, out);
}

// Round 16
// 220.084 us; speedup vs baseline: 1.0480x; 1.0480x over previous
//
#include <hip/hip_runtime.h>

#define N_NODES 10000
#define N_EDGES 100000
#define F_NODE 128
#define HEADS 8
#define HC 1024
#define NCOLS2 2432  // xg(1024) v(1024) skip(128) qwe(128) du(8) sv(8) pad(112)
#define NB2 (NCOLS2 / 128)   // 19
#define SLOT_CAP 48
#define XV_STRIDE 2048       // bytes: [x fp8 128][sv f32 32][pad][v fp8 @1024]

typedef __attribute__((ext_vector_type(8))) short bf16x8;
typedef __attribute__((ext_vector_type(4))) float f32x4;
typedef __attribute__((ext_vector_type(2))) float f32x2;

__device__ __forceinline__ void atomAddF(float* p, float v) {
    unsafeAtomicAdd(p, v);
}
__device__ __forceinline__ unsigned short f2bf(float f) {
    union { float f; unsigned u; } c; c.f = f;
    unsigned u = c.u + 0x7fffu + ((c.u >> 16) & 1u);  // RNE
    return (unsigned short)(u >> 16);
}
__device__ __forceinline__ float bLo(unsigned x) {
    union { unsigned u; float f; } c; c.u = x << 16; return c.f;
}
__device__ __forceinline__ float bHi(unsigned x) {
    union { unsigned u; float f; } c; c.u = x & 0xffff0000u; return c.f;
}
__device__ __forceinline__ float bf2f(unsigned short u) {
    union { unsigned u; float f; } c; c.u = ((unsigned)u) << 16; return c.f;
}
__device__ __forceinline__ unsigned pk4fp8(unsigned a, unsigned b) {
    int w = __builtin_amdgcn_cvt_pk_fp8_f32(bLo(a), bHi(a), 0, false);
    w = __builtin_amdgcn_cvt_pk_fp8_f32(bLo(b), bHi(b), w, true);
    return (unsigned)w;
}
__device__ __forceinline__ float dot128(const float* __restrict__ a,
                                        const float* __restrict__ b) {
    const float4* a4 = (const float4*)a;
    const float4* b4 = (const float4*)b;
    float s = 0.f;
    #pragma unroll
    for (int c = 0; c < 32; ++c) {
        float4 x4 = a4[c], y4 = b4[c];
        s += x4.x * y4.x + x4.y * y4.y + x4.z * y4.z + x4.w * y4.w;
    }
    return s;
}

// ================= fused prep: conv + edge-scatter + W build =================
#define PREP_A 1250
#define PREP_B (PREP_A + NCOLS2 / 2)       // 2466
#define PREP_C (PREP_B + 10)               // 2476
#define PREP_D (PREP_C + 64)               // 2540
__global__ __launch_bounds__(256) void prep_all(
    const float* __restrict__ x, unsigned short* __restrict__ xb,
    unsigned char* __restrict__ xv, const int* __restrict__ ei,
    int* __restrict__ cnt, int2* __restrict__ slots,
    const float* __restrict__ Wq, const float* __restrict__ Wk,
    const float* __restrict__ Wv, const float* __restrict__ Wskip,
    const float* __restrict__ We, const float* __restrict__ bq,
    const float* __restrict__ bk, const float* __restrict__ bv,
    const float* __restrict__ bskip, unsigned short* __restrict__ wt,
    float* __restrict__ bias, unsigned short* __restrict__ w2t) {
    int tid = threadIdx.x;
    if (blockIdx.x < PREP_A) {
        int i = blockIdx.x * 256 + tid;
        float4 f = ((const float4*)x)[i];
        ushort4 o;
        o.x = f2bf(f.x); o.y = f2bf(f.y); o.z = f2bf(f.z); o.w = f2bf(f.w);
        ((ushort4*)xb)[i] = o;
        int w = __builtin_amdgcn_cvt_pk_fp8_f32(f.x, f.y, 0, false);
        w = __builtin_amdgcn_cvt_pk_fp8_f32(f.z, f.w, w, true);
        ((unsigned*)xv)[((i >> 5) << 9) + (i & 31)] = (unsigned)w;
        if (i < N_EDGES) {
            int src = ei[i];
            int dst = ei[N_EDGES + i];
            int pos = atomicAdd(&cnt[dst], 1);
            if (pos < SLOT_CAP) slots[(size_t)dst * SLOT_CAP + pos] = make_int2(src, i);
        }
    } else if (blockIdx.x < PREP_B) {
        __shared__ float wesh[2][128];
        int bi = blockIdx.x - PREP_A;
        int cid = tid >> 7, d = tid & 127;
        int n = 2 * bi + cid;
        float val;
        if (n < 1024) {           // G_h[d,f2] = sum_c Wq[d,hc] Wk[f2,hc]
            int h = n >> 7, f2 = n & 127;
            wesh[cid][d] = Wk[(size_t)f2 * HC + h * 128 + d];
            __syncthreads();
            val = dot128(Wq + (size_t)d * HC + h * 128, wesh[cid]);
        } else if (n < 2048) {
            val = Wv[(size_t)d * HC + (n - 1024)];
        } else if (n < 2176) {
            val = Wskip[(size_t)d * 128 + (n - 2048)];
        } else if (n < 2304) {
            int hf = n - 2176, h = hf >> 4, f = hf & 15;
            wesh[cid][d] = We[(size_t)f * HC + h * 128 + d];
            __syncthreads();
            val = dot128(Wq + (size_t)d * HC + h * 128, wesh[cid]);
        } else if (n < 2312) {    // du col: Wq_h . bk_h
            int h = n - 2304;
            wesh[cid][d] = bk[h * 128 + d];
            __syncthreads();
            val = dot128(Wq + (size_t)d * HC + h * 128, wesh[cid]);
        } else if (n < 2320) {    // sv col: Wk_h . bq_h
            int h = n - 2312;
            wesh[cid][d] = bq[h * 128 + d];
            __syncthreads();
            val = dot128(Wk + (size_t)d * HC + h * 128, wesh[cid]);
        } else {
            val = 0.f;
        }
        wt[(size_t)n * 128 + d] = f2bf(val);
    } else if (blockIdx.x < PREP_C) {
        int n = (blockIdx.x - PREP_B) * 256 + tid;
        if (n >= NCOLS2) return;
        float val;
        if (n < 1024) val = 0.f;
        else if (n < 2048) val = bv[n - 1024];
        else if (n < 2176) val = bskip[n - 2048];
        else if (n < 2304) {
            int hf = n - 2176, h = hf >> 4, f = hf & 15;
            float s = 0.f;
            for (int c = 0; c < 128; ++c)
                s += bq[h * 128 + c] * We[(size_t)f * HC + h * 128 + c];
            val = s;
        } else if (n < 2312) {    // c_h = bq_h . bk_h
            int h = n - 2304;
            float s = 0.f;
            for (int c = 0; c < 128; ++c) s += bq[h * 128 + c] * bk[h * 128 + c];
            val = s;
        } else val = 0.f;
        bias[n] = val;
    } else {
        int c = (blockIdx.x - PREP_C) * 2 + (tid >> 7);
        int d = tid & 127;
        int h = d >> 4, f = d & 15;
        w2t[(size_t)c * 128 + d] = f2bf(We[(size_t)f * HC + h * 128 + c] * 0.125f);
    }
}

// ---- MFMA GEMM: [10000,128]bf16 x [128,2432]bf16, LDS-staged ----
__global__ __launch_bounds__(256) void gemm_mfma(
    const unsigned short* __restrict__ xb, const unsigned short* __restrict__ wt,
    const float* __restrict__ bias, unsigned char* __restrict__ xgf8,
    unsigned char* __restrict__ xv, unsigned short* __restrict__ sqb,
    float* __restrict__ du) {
    __shared__ unsigned short lds[18432];
    unsigned short (*As)[72] = (unsigned short(*)[72])lds;
    unsigned short (*Bs)[72] = (unsigned short(*)[72])(lds + 9216);
    int tid = threadIdx.x;
    int n0 = blockIdx.x * 128, m0 = blockIdx.y * 128;
    int w = tid >> 6, lane = tid & 63;
    int wm = (w >> 1) * 64, wn = (w & 1) * 64;
    int quad = lane >> 4, l16 = lane & 15;
    f32x4 acc[4][4];
    #pragma unroll
    for (int i = 0; i < 4; ++i)
        #pragma unroll
        for (int j = 0; j < 4; ++j) acc[i][j] = (f32x4){0.f, 0.f, 0.f, 0.f};

    for (int ko = 0; ko < 128; ko += 64) {
        #pragma unroll
        for (int tI = 0; tI < 4; ++tI) {
            int cId = tid + tI * 256;
            int r = cId >> 3, c8 = (cId & 7) << 3;
            int gr = m0 + r;
            uint4 av = make_uint4(0u, 0u, 0u, 0u);
            if (gr < N_NODES)
                av = *(const uint4*)(xb + (size_t)gr * 128 + ko + c8);
            *(uint4*)(&As[r][c8]) = av;
            *(uint4*)(&Bs[r][c8]) =
                *(const uint4*)(wt + (size_t)(n0 + r) * 128 + ko + c8);
        }
        __syncthreads();
        #pragma unroll
        for (int ks = 0; ks < 64; ks += 32) {
            bf16x8 a[4], b[4];
            #pragma unroll
            for (int mt = 0; mt < 4; ++mt)
                a[mt] = *(const bf16x8*)&As[wm + mt * 16 + l16][ks + quad * 8];
            #pragma unroll
            for (int nt = 0; nt < 4; ++nt)
                b[nt] = *(const bf16x8*)&Bs[wn + nt * 16 + l16][ks + quad * 8];
            #pragma unroll
            for (int mt = 0; mt < 4; ++mt)
                #pragma unroll
                for (int nt = 0; nt < 4; ++nt)
                    acc[mt][nt] = __builtin_amdgcn_mfma_f32_16x16x32_bf16(
                        a[mt], b[nt], acc[mt][nt], 0, 0, 0);
        }
        __syncthreads();
    }
    int nt0 = n0 >> 7;  // 0..7 xg, 8..15 v, 16/17 sq, 18 du/sv
    if (nt0 >= 16) {
        #pragma unroll
        for (int mt = 0; mt < 4; ++mt)
            #pragma unroll
            for (int r = 0; r < 4; ++r) {
                int row = m0 + wm + mt * 16 + quad * 4 + r;
                if (row >= N_NODES) continue;
                #pragma unroll
                for (int nt = 0; nt < 4; ++nt) {
                    int col = n0 + wn + nt * 16 + l16;
                    float val = acc[mt][nt][r] + bias[col];
                    if (col < 2304) {
                        sqb[(size_t)row * 256 + (col - 2048)] = f2bf(val);
                    } else if (col < 2312) {
                        du[(size_t)row * 8 + (col - 2304)] = val;
                    } else if (col < 2320) {
                        *(float*)(xv + (size_t)row * XV_STRIDE + 128 +
                                  (col - 2312) * 4) = val;
                    }
                }
            }
    } else {
        unsigned short* wst = lds + w * 4608;
        #pragma unroll
        for (int mt = 0; mt < 4; ++mt)
            #pragma unroll
            for (int r = 0; r < 4; ++r) {
                int rl = mt * 16 + quad * 4 + r;
                #pragma unroll
                for (int nt = 0; nt < 4; ++nt) {
                    int cl = nt * 16 + l16;
                    wst[rl * 72 + cl] = f2bf(acc[mt][nt][r] + bias[n0 + wn + cl]);
                }
            }
        int colbase = (n0 & 1023) + wn;
        #pragma unroll
        for (int p = 0; p < 4; ++p) {
            int rl = p * 16 + (lane >> 2);
            int row = m0 + wm + rl;
            if (row < N_NODES) {
                const uint4* sp = (const uint4*)(wst + rl * 72 + (lane & 3) * 16);
                uint4 u0 = sp[0], u1 = sp[1];
                uint4 o;
                o.x = pk4fp8(u0.x, u0.y);
                o.y = pk4fp8(u0.z, u0.w);
                o.z = pk4fp8(u1.x, u1.y);
                o.w = pk4fp8(u1.z, u1.w);
                if (nt0 < 8) {
                    *(uint4*)(xgf8 + (size_t)row * 1024 + colbase +
                              (lane & 3) * 16) = o;
                } else {
                    *(uint4*)(xv + (size_t)row * XV_STRIDE + 1024 + colbase +
                              (lane & 3) * 16) = o;
                }
            }
        }
    }
}

// -------- node attention: FOUR WAVES PER NODE, 2-edge unroll ----
// Direct slot loads (R14 style); quarter-split edge list; LDS merge.
__global__ __launch_bounds__(256) void node_kernel(
    const unsigned char* __restrict__ xgf8, const unsigned char* __restrict__ xv,
    const unsigned short* __restrict__ sqb, const float* __restrict__ ea,
    const float* __restrict__ du, const int2* __restrict__ slots,
    const int* __restrict__ cnt, unsigned short* __restrict__ ttb,
    float* __restrict__ hsum) {
    __shared__ float lva[3][16][64];   // waves 0..2 publish; conflict-free
    __shared__ float lst[3][3][64];    // s, t0, t1
    int t = threadIdx.x;
    int w = t >> 6, lane = t & 63;
    int lh = lane & 7, h = lane >> 3;
    const float scale = 0.08838834764831845f;  // 1/sqrt(128)
    int n = blockIdx.x;   // grid = 10000

    uint4 gq = *(const uint4*)(xgf8 + (size_t)n * 1024 + 16 * lane);
    float gf[16];
    {
        f32x2 p;
        p = __builtin_amdgcn_cvt_pk_f32_fp8(gq.x, false); gf[0] = p.x; gf[1] = p.y;
        p = __builtin_amdgcn_cvt_pk_f32_fp8(gq.x, true);  gf[2] = p.x; gf[3] = p.y;
        p = __builtin_amdgcn_cvt_pk_f32_fp8(gq.y, false); gf[4] = p.x; gf[5] = p.y;
        p = __builtin_amdgcn_cvt_pk_f32_fp8(gq.y, true);  gf[6] = p.x; gf[7] = p.y;
        p = __builtin_amdgcn_cvt_pk_f32_fp8(gq.z, false); gf[8] = p.x; gf[9] = p.y;
        p = __builtin_amdgcn_cvt_pk_f32_fp8(gq.z, true);  gf[10] = p.x; gf[11] = p.y;
        p = __builtin_amdgcn_cvt_pk_f32_fp8(gq.w, false); gf[12] = p.x; gf[13] = p.y;
        p = __builtin_amdgcn_cvt_pk_f32_fp8(gq.w, true);  gf[14] = p.x; gf[15] = p.y;
    }
    ushort2 qwu = *(const ushort2*)(sqb + (size_t)n * 256 + 128 + h * 16 + 2 * lh);
    float qwx = bf2f(qwu.x), qwy = bf2f(qwu.y);
    float du_r = du[(size_t)n * 8 + h];

    int cn = cnt[n];
    cn = (cn > SLOT_CAP) ? SLOT_CAP : cn;
    int quarter = (cn + 3) >> 2;
    int begin = w * quarter;
    int end = begin + quarter;
    end = (end < cn) ? end : cn;
    const int2* sp = slots + (size_t)n * SLOT_CAP;
    float va[16];
    #pragma unroll
    for (int i = 0; i < 16; ++i) va[i] = 0.f;
    float s_reg = 0.f, t0 = 0.f, t1 = 0.f;

    for (int ii = begin; ii < end; ii += 2) {
        bool bvalid = (ii + 1 < end);
        int i1 = bvalid ? ii + 1 : ii;
        int2 sa = sp[ii], sb = sp[i1];
        const unsigned char* baseA = xv + ((size_t)sa.x << 11);
        const unsigned char* baseB = xv + ((size_t)sb.x << 11);
        uint4 xA = *(const uint4*)(baseA + lh * 16);
        uint4 xB = *(const uint4*)(baseB + lh * 16);
        uint4 vA = *(const uint4*)(baseA + 1024 + lane * 16);
        uint4 vB = *(const uint4*)(baseB + 1024 + lane * 16);
        float svA = *(const float*)(baseA + 128 + h * 4);
        float svB = *(const float*)(baseB + 128 + h * 4);
        float2 eavA = *(const float2*)(ea + (size_t)sa.y * 16 + 2 * lh);
        float2 eavB = *(const float2*)(ea + (size_t)sb.y * 16 + 2 * lh);

        // ----- edge A -----
        {
            float d = eavA.x * qwx + eavA.y * qwy;
            f32x2 p;
            p = __builtin_amdgcn_cvt_pk_f32_fp8(xA.x, false); d += gf[0]*p.x + gf[1]*p.y;
            p = __builtin_amdgcn_cvt_pk_f32_fp8(xA.x, true);  d += gf[2]*p.x + gf[3]*p.y;
            p = __builtin_amdgcn_cvt_pk_f32_fp8(xA.y, false); d += gf[4]*p.x + gf[5]*p.y;
            p = __builtin_amdgcn_cvt_pk_f32_fp8(xA.y, true);  d += gf[6]*p.x + gf[7]*p.y;
            p = __builtin_amdgcn_cvt_pk_f32_fp8(xA.z, false); d += gf[8]*p.x + gf[9]*p.y;
            p = __builtin_amdgcn_cvt_pk_f32_fp8(xA.z, true);  d += gf[10]*p.x + gf[11]*p.y;
            p = __builtin_amdgcn_cvt_pk_f32_fp8(xA.w, false); d += gf[12]*p.x + gf[13]*p.y;
            p = __builtin_amdgcn_cvt_pk_f32_fp8(xA.w, true);  d += gf[14]*p.x + gf[15]*p.y;
            d += __shfl_xor(d, 1); d += __shfl_xor(d, 2); d += __shfl_xor(d, 4);
            float a = __expf((d + du_r + svA) * scale);
            s_reg += a;
            t0 += a * eavA.x; t1 += a * eavA.y;
            p = __builtin_amdgcn_cvt_pk_f32_fp8(vA.x, false); va[0] += a*p.x; va[1] += a*p.y;
            p = __builtin_amdgcn_cvt_pk_f32_fp8(vA.x, true);  va[2] += a*p.x; va[3] += a*p.y;
            p = __builtin_amdgcn_cvt_pk_f32_fp8(vA.y, false); va[4] += a*p.x; va[5] += a*p.y;
            p = __builtin_amdgcn_cvt_pk_f32_fp8(vA.y, true);  va[6] += a*p.x; va[7] += a*p.y;
            p = __builtin_amdgcn_cvt_pk_f32_fp8(vA.z, false); va[8] += a*p.x; va[9] += a*p.y;
            p = __builtin_amdgcn_cvt_pk_f32_fp8(vA.z, true);  va[10] += a*p.x; va[11] += a*p.y;
            p = __builtin_amdgcn_cvt_pk_f32_fp8(vA.w, false); va[12] += a*p.x; va[13] += a*p.y;
            p = __builtin_amdgcn_cvt_pk_f32_fp8(vA.w, true);  va[14] += a*p.x; va[15] += a*p.y;
        }
        // ----- edge B (masked if duplicate) -----
        {
            float d = eavB.x * qwx + eavB.y * qwy;
            f32x2 p;
            p = __builtin_amdgcn_cvt_pk_f32_fp8(xB.x, false); d += gf[0]*p.x + gf[1]*p.y;
            p = __builtin_amdgcn_cvt_pk_f32_fp8(xB.x, true);  d += gf[2]*p.x + gf[3]*p.y;
            p = __builtin_amdgcn_cvt_pk_f32_fp8(xB.y, false); d += gf[4]*p.x + gf[5]*p.y;
            p = __builtin_amdgcn_cvt_pk_f32_fp8(xB.y, true);  d += gf[6]*p.x + gf[7]*p.y;
            p = __builtin_amdgcn_cvt_pk_f32_fp8(xB.z, false); d += gf[8]*p.x + gf[9]*p.y;
            p = __builtin_amdgcn_cvt_pk_f32_fp8(xB.z, true);  d += gf[10]*p.x + gf[11]*p.y;
            p = __builtin_amdgcn_cvt_pk_f32_fp8(xB.w, false); d += gf[12]*p.x + gf[13]*p.y;
            p = __builtin_amdgcn_cvt_pk_f32_fp8(xB.w, true);  d += gf[14]*p.x + gf[15]*p.y;
            d += __shfl_xor(d, 1); d += __shfl_xor(d, 2); d += __shfl_xor(d, 4);
            float a = __expf((d + du_r + svB) * scale);
            a = bvalid ? a : 0.f;
            s_reg += a;
            t0 += a * eavB.x; t1 += a * eavB.y;
            p = __builtin_amdgcn_cvt_pk_f32_fp8(vB.x, false); va[0] += a*p.x; va[1] += a*p.y;
            p = __builtin_amdgcn_cvt_pk_f32_fp8(vB.x, true);  va[2] += a*p.x; va[3] += a*p.y;
            p = __builtin_amdgcn_cvt_pk_f32_fp8(vB.y, false); va[4] += a*p.x; va[5] += a*p.y;
            p = __builtin_amdgcn_cvt_pk_f32_fp8(vB.y, true);  va[6] += a*p.x; va[7] += a*p.y;
            p = __builtin_amdgcn_cvt_pk_f32_fp8(vB.z, false); va[8] += a*p.x; va[9] += a*p.y;
            p = __builtin_amdgcn_cvt_pk_f32_fp8(vB.z, true);  va[10] += a*p.x; va[11] += a*p.y;
            p = __builtin_amdgcn_cvt_pk_f32_fp8(vB.w, false); va[12] += a*p.x; va[13] += a*p.y;
            p = __builtin_amdgcn_cvt_pk_f32_fp8(vB.w, true);  va[14] += a*p.x; va[15] += a*p.y;
        }
    }
    // merge 4 waves through LDS: waves 0..2 publish, wave 3 combines
    if (w < 3) {
        #pragma unroll
        for (int i = 0; i < 16; ++i) lva[w][i][lane] = va[i];
        lst[w][0][lane] = s_reg;
        lst[w][1][lane] = t0;
        lst[w][2][lane] = t1;
    }
    __syncthreads();
    if (w == 3) {
        #pragma unroll
        for (int m = 0; m < 3; ++m) {
            s_reg += lst[m][0][lane];
            t0 += lst[m][1][lane];
            t1 += lst[m][2][lane];
            #pragma unroll
            for (int i = 0; i < 16; ++i) va[i] += lva[m][i][lane];
        }
        float inv = 1.f / (s_reg + 1e-16f);
        ushort2 tw;
        tw.x = f2bf(t0 * inv);
        tw.y = f2bf(t1 * inv);
        *(ushort2*)(ttb + (size_t)n * 128 + h * 16 + 2 * lh) = tw;
        float sc = inv * 0.125f;
        #pragma unroll
        for (int i = 0; i < 16; ++i) {
            float o = va[i] * sc;
            o += __shfl_xor(o, 8);
            o += __shfl_xor(o, 16);
            o += __shfl_xor(o, 32);
            va[i] = o;
        }
        if (lane < 8) {
            float* hp = hsum + (size_t)n * 128 + lane * 16;
            #pragma unroll
            for (int p2 = 0; p2 < 4; ++p2) {
                float4 h4 = make_float4(va[4 * p2], va[4 * p2 + 1],
                                        va[4 * p2 + 2], va[4 * p2 + 3]);
                ((float4*)hp)[p2] = h4;
            }
        }
    }
}

// -- out GEMM: m-tile 32 (313 blocks), LDS-staged A, epilogue + final -------
__global__ __launch_bounds__(256) void out_gemm(
    const unsigned short* __restrict__ ttb, const unsigned short* __restrict__ w2t,
    const float* __restrict__ hsum, const unsigned short* __restrict__ sqb,
    float* __restrict__ pooled, int* __restrict__ done,
    const float* __restrict__ Wd, const float* __restrict__ bd,
    float* __restrict__ out) {
    __shared__ unsigned short As[32][136];
    __shared__ float pool_sh[128];
    __shared__ int last_sh;
    int tid = threadIdx.x;
    int m0 = blockIdx.x * 32;
    int w = tid >> 6, lane = tid & 63;
    int wm = (w >> 1) * 16, wn = (w & 1) * 64;
    int quad = lane >> 4, l16 = lane & 15;
    if (tid < 128) pool_sh[tid] = 0.f;
    #pragma unroll
    for (int tI = 0; tI < 2; ++tI) {
        int cId = tid + tI * 256;
        int r = cId >> 4, c8 = (cId & 15) << 3;
        int gr = m0 + r;
        uint4 av = make_uint4(0u, 0u, 0u, 0u);
        if (gr < N_NODES)
            av = *(const uint4*)(ttb + (size_t)gr * 128 + c8);
        *(uint4*)(&As[r][c8]) = av;
    }
    __syncthreads();
    f32x4 acc[4];
    #pragma unroll
    for (int j = 0; j < 4; ++j) acc[j] = (f32x4){0.f, 0.f, 0.f, 0.f};

    const unsigned short* bb = w2t + (size_t)(wn + l16) * 128 + quad * 8;
    #pragma unroll
    for (int ks = 0; ks < 128; ks += 32) {
        bf16x8 a = *(const bf16x8*)&As[wm + l16][ks + quad * 8];
        #pragma unroll
        for (int nt = 0; nt < 4; ++nt) {
            bf16x8 b = *(const bf16x8*)(bb + (size_t)nt * 16 * 128 + ks);
            acc[nt] = __builtin_amdgcn_mfma_f32_16x16x32_bf16(a, b, acc[nt], 0, 0, 0);
        }
    }
    float pl[4] = {0.f, 0.f, 0.f, 0.f};
    #pragma unroll
    for (int r = 0; r < 4; ++r) {
        int row = m0 + wm + quad * 4 + r;
        if (row >= N_NODES) continue;
        #pragma unroll
        for (int nt = 0; nt < 4; ++nt) {
            int col = wn + nt * 16 + l16;
            float val = acc[nt][r] + hsum[(size_t)row * 128 + col]
                        + bf2f(sqb[(size_t)row * 256 + col]);
            pl[nt] += fmaxf(val, 0.f);
        }
    }
    #pragma unroll
    for (int nt = 0; nt < 4; ++nt)
        atomicAdd(&pool_sh[wn + nt * 16 + l16], pl[nt]);
    __syncthreads();
    if (tid < 128) atomAddF(&pooled[tid], pool_sh[tid]);
    __threadfence();
    if (tid == 0) last_sh = (atomicAdd(done, 1) == (int)gridDim.x - 1);
    __syncthreads();
    if (last_sh && tid < 64) {
        float p0 = __hip_atomic_load(&pooled[2 * tid], __ATOMIC_RELAXED,
                                     __HIP_MEMORY_SCOPE_AGENT);
        float p1 = __hip_atomic_load(&pooled[2 * tid + 1], __ATOMIC_RELAXED,
                                     __HIP_MEMORY_SCOPE_AGENT);
        float vv = p0 * Wd[2 * tid] + p1 * Wd[2 * tid + 1];
        vv += __shfl_xor(vv, 1);  vv += __shfl_xor(vv, 2);  vv += __shfl_xor(vv, 4);
        vv += __shfl_xor(vv, 8);  vv += __shfl_xor(vv, 16); vv += __shfl_xor(vv, 32);
        if (tid == 0) out[0] = vv + bd[0];
    }
}

extern "C" void kernel_launch(void* const* d_in, const int* in_sizes, int n_in,
                              void* d_out, int out_size, void* d_ws, size_t ws_size,
                              hipStream_t stream) {
    const float* x     = (const float*)d_in[0];
    const float* eattr = (const float*)d_in[1];
    const int*   ei    = (const int*)d_in[2];
    const float* Wq    = (const float*)d_in[3];
    const float* bq    = (const float*)d_in[4];
    const float* Wk    = (const float*)d_in[5];
    const float* bk    = (const float*)d_in[6];
    const float* Wv    = (const float*)d_in[7];
    const float* bv    = (const float*)d_in[8];
    const float* We    = (const float*)d_in[9];
    const float* Wskip = (const float*)d_in[10];
    const float* bskip = (const float*)d_in[11];
    const float* Wd    = (const float*)d_in[12];
    const float* bd    = (const float*)d_in[13];
    float* out = (float*)d_out;

    char* ws = (char*)d_ws;
    unsigned char*  xgf8 = (unsigned char*)(ws + 0);           // 10,240,000
    unsigned char*  xv   = (unsigned char*)(ws + 10240000);    // 20,480,000
    unsigned short* sqb  = (unsigned short*)(ws + 30720000);   //  5,120,000
    float* hsum = (float*)(ws + 35840000);                     //  5,120,000
    unsigned short* xb   = (unsigned short*)(ws + 40960000);   //  2,560,000
    unsigned short* ttb  = xb;  // reuse: xb dead after gemm_mfma
    float* du   = (float*)(ws + 43520000);                     //    320,000
    unsigned short* wt   = (unsigned short*)(ws + 43840000);   //    622,592
    float* bias = (float*)(ws + 44462592);                     //      9,728
    unsigned short* w2t  = (unsigned short*)(ws + 44472320);   //     32,768
    int* cnt    = (int*)(ws + 44505088);                       //     40,000
    float* pooled = (float*)(ws + 44545088);                   //        512
    int* done   = (int*)(ws + 44545600);                       //         16
    int2* slots = (int2*)(ws + 44545616);                      //  3,840,000

    hipMemsetAsync(cnt, 0, 40000 + 512 + 16, stream);

    prep_all<<<PREP_D, 256, 0, stream>>>(
        x, xb, xv, ei, cnt, slots, Wq, Wk, Wv, Wskip, We, bq, bk, bv, bskip,
        wt, bias, w2t);

    gemm_mfma<<<dim3(NB2, (N_NODES + 127) / 128), 256, 0, stream>>>(
        xb, wt, bias, xgf8, xv, sqb, du);

    node_kernel<<<N_NODES, 256, 0, stream>>>(
        xgf8, xv, sqb, eattr, du, slots, cnt, ttb, hsum);

    out_gemm<<<(N_NODES + 31) / 32, 256, 0, stream>>>(
        ttb, w2t, hsum, sqb, pooled, done, Wd, bd, out);
}

// Round 17
// 204.492 us; speedup vs baseline: 1.1279x; 1.0763x over previous
//
#include <hip/hip_runtime.h>

#define N_NODES 10000
#define N_EDGES 100000
#define F_NODE 128
#define HEADS 8
#define HC 1024
#define NCOLS2 2432  // xg(1024) v(1024) skip(128) qwe(128) du(8) sv(8) pad(112)
#define NB2 (NCOLS2 / 128)   // 19
#define SLOT_CAP 48
#define XV_STRIDE 2048       // bytes: [x fp8 128][sv f32 32][pad][v fp8 @1024]

typedef __attribute__((ext_vector_type(8))) short bf16x8;
typedef __attribute__((ext_vector_type(4))) float f32x4;
typedef __attribute__((ext_vector_type(2))) float f32x2;

__device__ __forceinline__ void atomAddF(float* p, float v) {
    unsafeAtomicAdd(p, v);
}
__device__ __forceinline__ unsigned short f2bf(float f) {
    union { float f; unsigned u; } c; c.f = f;
    unsigned u = c.u + 0x7fffu + ((c.u >> 16) & 1u);  // RNE
    return (unsigned short)(u >> 16);
}
__device__ __forceinline__ float bLo(unsigned x) {
    union { unsigned u; float f; } c; c.u = x << 16; return c.f;
}
__device__ __forceinline__ float bHi(unsigned x) {
    union { unsigned u; float f; } c; c.u = x & 0xffff0000u; return c.f;
}
__device__ __forceinline__ float bf2f(unsigned short u) {
    union { unsigned u; float f; } c; c.u = ((unsigned)u) << 16; return c.f;
}
__device__ __forceinline__ unsigned pk4fp8(unsigned a, unsigned b) {
    int w = __builtin_amdgcn_cvt_pk_fp8_f32(bLo(a), bHi(a), 0, false);
    w = __builtin_amdgcn_cvt_pk_fp8_f32(bLo(b), bHi(b), w, true);
    return (unsigned)w;
}
__device__ __forceinline__ float dot128(const float* __restrict__ a,
                                        const float* __restrict__ b) {
    const float4* a4 = (const float4*)a;
    const float4* b4 = (const float4*)b;
    float s = 0.f;
    #pragma unroll
    for (int c = 0; c < 32; ++c) {
        float4 x4 = a4[c], y4 = b4[c];
        s += x4.x * y4.x + x4.y * y4.y + x4.z * y4.z + x4.w * y4.w;
    }
    return s;
}

// ================= fused prep: conv + edge-scatter + W build =================
#define PREP_A 1250
#define PREP_B (PREP_A + NCOLS2 / 2)       // 2466
#define PREP_C (PREP_B + 10)               // 2476
#define PREP_D (PREP_C + 64)               // 2540
__global__ __launch_bounds__(256) void prep_all(
    const float* __restrict__ x, unsigned short* __restrict__ xb,
    unsigned char* __restrict__ xv, const int* __restrict__ ei,
    int* __restrict__ cnt, int2* __restrict__ slots,
    const float* __restrict__ Wq, const float* __restrict__ Wk,
    const float* __restrict__ Wv, const float* __restrict__ Wskip,
    const float* __restrict__ We, const float* __restrict__ bq,
    const float* __restrict__ bk, const float* __restrict__ bv,
    const float* __restrict__ bskip, unsigned short* __restrict__ wt,
    float* __restrict__ bias, unsigned short* __restrict__ w2t) {
    int tid = threadIdx.x;
    if (blockIdx.x < PREP_A) {
        int i = blockIdx.x * 256 + tid;
        float4 f = ((const float4*)x)[i];
        ushort4 o;
        o.x = f2bf(f.x); o.y = f2bf(f.y); o.z = f2bf(f.z); o.w = f2bf(f.w);
        ((ushort4*)xb)[i] = o;
        int w = __builtin_amdgcn_cvt_pk_fp8_f32(f.x, f.y, 0, false);
        w = __builtin_amdgcn_cvt_pk_fp8_f32(f.z, f.w, w, true);
        ((unsigned*)xv)[((i >> 5) << 9) + (i & 31)] = (unsigned)w;
        if (i < N_EDGES) {
            int src = ei[i];
            int dst = ei[N_EDGES + i];
            int pos = atomicAdd(&cnt[dst], 1);
            if (pos < SLOT_CAP) slots[(size_t)dst * SLOT_CAP + pos] = make_int2(src, i);
        }
    } else if (blockIdx.x < PREP_B) {
        __shared__ float wesh[2][128];
        int bi = blockIdx.x - PREP_A;
        int cid = tid >> 7, d = tid & 127;
        int n = 2 * bi + cid;
        float val;
        if (n < 1024) {           // G_h[d,f2] = sum_c Wq[d,hc] Wk[f2,hc]
            int h = n >> 7, f2 = n & 127;
            wesh[cid][d] = Wk[(size_t)f2 * HC + h * 128 + d];
            __syncthreads();
            val = dot128(Wq + (size_t)d * HC + h * 128, wesh[cid]);
        } else if (n < 2048) {
            val = Wv[(size_t)d * HC + (n - 1024)];
        } else if (n < 2176) {
            val = Wskip[(size_t)d * 128 + (n - 2048)];
        } else if (n < 2304) {
            int hf = n - 2176, h = hf >> 4, f = hf & 15;
            wesh[cid][d] = We[(size_t)f * HC + h * 128 + d];
            __syncthreads();
            val = dot128(Wq + (size_t)d * HC + h * 128, wesh[cid]);
        } else if (n < 2312) {    // du col: Wq_h . bk_h
            int h = n - 2304;
            wesh[cid][d] = bk[h * 128 + d];
            __syncthreads();
            val = dot128(Wq + (size_t)d * HC + h * 128, wesh[cid]);
        } else if (n < 2320) {    // sv col: Wk_h . bq_h
            int h = n - 2312;
            wesh[cid][d] = bq[h * 128 + d];
            __syncthreads();
            val = dot128(Wk + (size_t)d * HC + h * 128, wesh[cid]);
        } else {
            val = 0.f;
        }
        wt[(size_t)n * 128 + d] = f2bf(val);
    } else if (blockIdx.x < PREP_C) {
        int n = (blockIdx.x - PREP_B) * 256 + tid;
        if (n >= NCOLS2) return;
        float val;
        if (n < 1024) val = 0.f;
        else if (n < 2048) val = bv[n - 1024];
        else if (n < 2176) val = bskip[n - 2048];
        else if (n < 2304) {
            int hf = n - 2176, h = hf >> 4, f = hf & 15;
            float s = 0.f;
            for (int c = 0; c < 128; ++c)
                s += bq[h * 128 + c] * We[(size_t)f * HC + h * 128 + c];
            val = s;
        } else if (n < 2312) {    // c_h = bq_h . bk_h
            int h = n - 2304;
            float s = 0.f;
            for (int c = 0; c < 128; ++c) s += bq[h * 128 + c] * bk[h * 128 + c];
            val = s;
        } else val = 0.f;
        bias[n] = val;
    } else {
        int c = (blockIdx.x - PREP_C) * 2 + (tid >> 7);
        int d = tid & 127;
        int h = d >> 4, f = d & 15;
        w2t[(size_t)c * 128 + d] = f2bf(We[(size_t)f * HC + h * 128 + c] * 0.125f);
    }
}

// ---- MFMA GEMM: [10000,128]bf16 x [128,2432]bf16, LDS-staged ----
__global__ __launch_bounds__(256) void gemm_mfma(
    const unsigned short* __restrict__ xb, const unsigned short* __restrict__ wt,
    const float* __restrict__ bias, unsigned char* __restrict__ xgf8,
    unsigned char* __restrict__ xv, unsigned short* __restrict__ sqb,
    float* __restrict__ du) {
    __shared__ unsigned short lds[18432];
    unsigned short (*As)[72] = (unsigned short(*)[72])lds;
    unsigned short (*Bs)[72] = (unsigned short(*)[72])(lds + 9216);
    int tid = threadIdx.x;
    int n0 = blockIdx.x * 128, m0 = blockIdx.y * 128;
    int w = tid >> 6, lane = tid & 63;
    int wm = (w >> 1) * 64, wn = (w & 1) * 64;
    int quad = lane >> 4, l16 = lane & 15;
    f32x4 acc[4][4];
    #pragma unroll
    for (int i = 0; i < 4; ++i)
        #pragma unroll
        for (int j = 0; j < 4; ++j) acc[i][j] = (f32x4){0.f, 0.f, 0.f, 0.f};

    for (int ko = 0; ko < 128; ko += 64) {
        #pragma unroll
        for (int tI = 0; tI < 4; ++tI) {
            int cId = tid + tI * 256;
            int r = cId >> 3, c8 = (cId & 7) << 3;
            int gr = m0 + r;
            uint4 av = make_uint4(0u, 0u, 0u, 0u);
            if (gr < N_NODES)
                av = *(const uint4*)(xb + (size_t)gr * 128 + ko + c8);
            *(uint4*)(&As[r][c8]) = av;
            *(uint4*)(&Bs[r][c8]) =
                *(const uint4*)(wt + (size_t)(n0 + r) * 128 + ko + c8);
        }
        __syncthreads();
        #pragma unroll
        for (int ks = 0; ks < 64; ks += 32) {
            bf16x8 a[4], b[4];
            #pragma unroll
            for (int mt = 0; mt < 4; ++mt)
                a[mt] = *(const bf16x8*)&As[wm + mt * 16 + l16][ks + quad * 8];
            #pragma unroll
            for (int nt = 0; nt < 4; ++nt)
                b[nt] = *(const bf16x8*)&Bs[wn + nt * 16 + l16][ks + quad * 8];
            #pragma unroll
            for (int mt = 0; mt < 4; ++mt)
                #pragma unroll
                for (int nt = 0; nt < 4; ++nt)
                    acc[mt][nt] = __builtin_amdgcn_mfma_f32_16x16x32_bf16(
                        a[mt], b[nt], acc[mt][nt], 0, 0, 0);
        }
        __syncthreads();
    }
    int nt0 = n0 >> 7;  // 0..7 xg, 8..15 v, 16/17 sq, 18 du/sv
    if (nt0 >= 16) {
        #pragma unroll
        for (int mt = 0; mt < 4; ++mt)
            #pragma unroll
            for (int r = 0; r < 4; ++r) {
                int row = m0 + wm + mt * 16 + quad * 4 + r;
                if (row >= N_NODES) continue;
                #pragma unroll
                for (int nt = 0; nt < 4; ++nt) {
                    int col = n0 + wn + nt * 16 + l16;
                    float val = acc[mt][nt][r] + bias[col];
                    if (col < 2304) {
                        sqb[(size_t)row * 256 + (col - 2048)] = f2bf(val);
                    } else if (col < 2312) {
                        du[(size_t)row * 8 + (col - 2304)] = val;
                    } else if (col < 2320) {
                        *(float*)(xv + (size_t)row * XV_STRIDE + 128 +
                                  (col - 2312) * 4) = val;
                    }
                }
            }
    } else {
        unsigned short* wst = lds + w * 4608;
        #pragma unroll
        for (int mt = 0; mt < 4; ++mt)
            #pragma unroll
            for (int r = 0; r < 4; ++r) {
                int rl = mt * 16 + quad * 4 + r;
                #pragma unroll
                for (int nt = 0; nt < 4; ++nt) {
                    int cl = nt * 16 + l16;
                    wst[rl * 72 + cl] = f2bf(acc[mt][nt][r] + bias[n0 + wn + cl]);
                }
            }
        int colbase = (n0 & 1023) + wn;
        #pragma unroll
        for (int p = 0; p < 4; ++p) {
            int rl = p * 16 + (lane >> 2);
            int row = m0 + wm + rl;
            if (row < N_NODES) {
                const uint4* sp = (const uint4*)(wst + rl * 72 + (lane & 3) * 16);
                uint4 u0 = sp[0], u1 = sp[1];
                uint4 o;
                o.x = pk4fp8(u0.x, u0.y);
                o.y = pk4fp8(u0.z, u0.w);
                o.z = pk4fp8(u1.x, u1.y);
                o.w = pk4fp8(u1.z, u1.w);
                if (nt0 < 8) {
                    *(uint4*)(xgf8 + (size_t)row * 1024 + colbase +
                              (lane & 3) * 16) = o;
                } else {
                    *(uint4*)(xv + (size_t)row * XV_STRIDE + 1024 + colbase +
                              (lane & 3) * 16) = o;
                }
            }
        }
    }
}

// -------- node attention: TWO WAVES PER NODE, 2-edge unroll + SW pipeline --
__global__ __launch_bounds__(256) void node_kernel(
    const unsigned char* __restrict__ xgf8, const unsigned char* __restrict__ xv,
    const unsigned short* __restrict__ sqb, const float* __restrict__ ea,
    const float* __restrict__ du, const int2* __restrict__ slots,
    const int* __restrict__ cnt, unsigned short* __restrict__ ttb,
    float* __restrict__ hsum) {
    __shared__ float lva[2][16][64];   // [ns][i][lane] -> conflict-free
    __shared__ float lst[2][3][64];    // s, t0, t1
    int t = threadIdx.x;
    int w = t >> 6, lane = t & 63;
    int ns = w >> 1;          // node slot in block (0/1)
    int half = w & 1;
    int lh = lane & 7, h = lane >> 3;
    const float scale = 0.08838834764831845f;  // 1/sqrt(128)
    int n = blockIdx.x * 2 + ns;   // grid = 5000 exactly

    uint4 gq = *(const uint4*)(xgf8 + (size_t)n * 1024 + 16 * lane);
    float gf[16];
    {
        f32x2 p;
        p = __builtin_amdgcn_cvt_pk_f32_fp8(gq.x, false); gf[0] = p.x; gf[1] = p.y;
        p = __builtin_amdgcn_cvt_pk_f32_fp8(gq.x, true);  gf[2] = p.x; gf[3] = p.y;
        p = __builtin_amdgcn_cvt_pk_f32_fp8(gq.y, false); gf[4] = p.x; gf[5] = p.y;
        p = __builtin_amdgcn_cvt_pk_f32_fp8(gq.y, true);  gf[6] = p.x; gf[7] = p.y;
        p = __builtin_amdgcn_cvt_pk_f32_fp8(gq.z, false); gf[8] = p.x; gf[9] = p.y;
        p = __builtin_amdgcn_cvt_pk_f32_fp8(gq.z, true);  gf[10] = p.x; gf[11] = p.y;
        p = __builtin_amdgcn_cvt_pk_f32_fp8(gq.w, false); gf[12] = p.x; gf[13] = p.y;
        p = __builtin_amdgcn_cvt_pk_f32_fp8(gq.w, true);  gf[14] = p.x; gf[15] = p.y;
    }
    ushort2 qwu = *(const ushort2*)(sqb + (size_t)n * 256 + 128 + h * 16 + 2 * lh);
    float qwx = bf2f(qwu.x), qwy = bf2f(qwu.y);
    float du_r = du[(size_t)n * 8 + h];

    int cn = cnt[n];
    cn = (cn > SLOT_CAP) ? SLOT_CAP : cn;
    int mid = (cn + 1) >> 1;
    int begin = half ? mid : 0;
    int end = half ? cn : mid;
    const int2* sp = slots + (size_t)n * SLOT_CAP;
    float va[16];
    #pragma unroll
    for (int i = 0; i < 16; ++i) va[i] = 0.f;
    float s_reg = 0.f, t0 = 0.f, t1 = 0.f;

    // ---- software pipeline: prefetch group (slots + gathers) ----
    uint4 xA, xB, vA, vB;
    float svA, svB;
    float2 eavA, eavB;
    bool bvalidA = false;
    if (begin < end) {
        bool bv0 = (begin + 1 < end);
        int i1 = bv0 ? begin + 1 : begin;
        int2 sa = sp[begin], sb = sp[i1];
        const unsigned char* baseA = xv + ((size_t)sa.x << 11);
        const unsigned char* baseB = xv + ((size_t)sb.x << 11);
        xA = *(const uint4*)(baseA + lh * 16);
        xB = *(const uint4*)(baseB + lh * 16);
        vA = *(const uint4*)(baseA + 1024 + lane * 16);
        vB = *(const uint4*)(baseB + 1024 + lane * 16);
        svA = *(const float*)(baseA + 128 + h * 4);
        svB = *(const float*)(baseB + 128 + h * 4);
        eavA = *(const float2*)(ea + (size_t)sa.y * 16 + 2 * lh);
        eavB = *(const float2*)(ea + (size_t)sb.y * 16 + 2 * lh);
        bvalidA = bv0;
    }

    for (int ii = begin; ii < end; ii += 2) {
        // prefetch next group (clamped to current on last iter; discarded)
        int nx = (ii + 2 < end) ? ii + 2 : ii;
        bool bvN = (nx + 1 < end);
        int n1 = bvN ? nx + 1 : nx;
        int2 sa2 = sp[nx], sb2 = sp[n1];
        const unsigned char* baseA2 = xv + ((size_t)sa2.x << 11);
        const unsigned char* baseB2 = xv + ((size_t)sb2.x << 11);
        uint4 xA2 = *(const uint4*)(baseA2 + lh * 16);
        uint4 xB2 = *(const uint4*)(baseB2 + lh * 16);
        uint4 vA2 = *(const uint4*)(baseA2 + 1024 + lane * 16);
        uint4 vB2 = *(const uint4*)(baseB2 + 1024 + lane * 16);
        float svA2 = *(const float*)(baseA2 + 128 + h * 4);
        float svB2 = *(const float*)(baseB2 + 128 + h * 4);
        float2 eavA2 = *(const float2*)(ea + (size_t)sa2.y * 16 + 2 * lh);
        float2 eavB2 = *(const float2*)(ea + (size_t)sb2.y * 16 + 2 * lh);

        // ----- edge A -----
        {
            float d = eavA.x * qwx + eavA.y * qwy;
            f32x2 p;
            p = __builtin_amdgcn_cvt_pk_f32_fp8(xA.x, false); d += gf[0]*p.x + gf[1]*p.y;
            p = __builtin_amdgcn_cvt_pk_f32_fp8(xA.x, true);  d += gf[2]*p.x + gf[3]*p.y;
            p = __builtin_amdgcn_cvt_pk_f32_fp8(xA.y, false); d += gf[4]*p.x + gf[5]*p.y;
            p = __builtin_amdgcn_cvt_pk_f32_fp8(xA.y, true);  d += gf[6]*p.x + gf[7]*p.y;
            p = __builtin_amdgcn_cvt_pk_f32_fp8(xA.z, false); d += gf[8]*p.x + gf[9]*p.y;
            p = __builtin_amdgcn_cvt_pk_f32_fp8(xA.z, true);  d += gf[10]*p.x + gf[11]*p.y;
            p = __builtin_amdgcn_cvt_pk_f32_fp8(xA.w, false); d += gf[12]*p.x + gf[13]*p.y;
            p = __builtin_amdgcn_cvt_pk_f32_fp8(xA.w, true);  d += gf[14]*p.x + gf[15]*p.y;
            d += __shfl_xor(d, 1); d += __shfl_xor(d, 2); d += __shfl_xor(d, 4);
            float a = __expf((d + du_r + svA) * scale);
            s_reg += a;
            t0 += a * eavA.x; t1 += a * eavA.y;
            p = __builtin_amdgcn_cvt_pk_f32_fp8(vA.x, false); va[0] += a*p.x; va[1] += a*p.y;
            p = __builtin_amdgcn_cvt_pk_f32_fp8(vA.x, true);  va[2] += a*p.x; va[3] += a*p.y;
            p = __builtin_amdgcn_cvt_pk_f32_fp8(vA.y, false); va[4] += a*p.x; va[5] += a*p.y;
            p = __builtin_amdgcn_cvt_pk_f32_fp8(vA.y, true);  va[6] += a*p.x; va[7] += a*p.y;
            p = __builtin_amdgcn_cvt_pk_f32_fp8(vA.z, false); va[8] += a*p.x; va[9] += a*p.y;
            p = __builtin_amdgcn_cvt_pk_f32_fp8(vA.z, true);  va[10] += a*p.x; va[11] += a*p.y;
            p = __builtin_amdgcn_cvt_pk_f32_fp8(vA.w, false); va[12] += a*p.x; va[13] += a*p.y;
            p = __builtin_amdgcn_cvt_pk_f32_fp8(vA.w, true);  va[14] += a*p.x; va[15] += a*p.y;
        }
        // ----- edge B (masked if duplicate) -----
        {
            float d = eavB.x * qwx + eavB.y * qwy;
            f32x2 p;
            p = __builtin_amdgcn_cvt_pk_f32_fp8(xB.x, false); d += gf[0]*p.x + gf[1]*p.y;
            p = __builtin_amdgcn_cvt_pk_f32_fp8(xB.x, true);  d += gf[2]*p.x + gf[3]*p.y;
            p = __builtin_amdgcn_cvt_pk_f32_fp8(xB.y, false); d += gf[4]*p.x + gf[5]*p.y;
            p = __builtin_amdgcn_cvt_pk_f32_fp8(xB.y, true);  d += gf[6]*p.x + gf[7]*p.y;
            p = __builtin_amdgcn_cvt_pk_f32_fp8(xB.z, false); d += gf[8]*p.x + gf[9]*p.y;
            p = __builtin_amdgcn_cvt_pk_f32_fp8(xB.z, true);  d += gf[10]*p.x + gf[11]*p.y;
            p = __builtin_amdgcn_cvt_pk_f32_fp8(xB.w, false); d += gf[12]*p.x + gf[13]*p.y;
            p = __builtin_amdgcn_cvt_pk_f32_fp8(xB.w, true);  d += gf[14]*p.x + gf[15]*p.y;
            d += __shfl_xor(d, 1); d += __shfl_xor(d, 2); d += __shfl_xor(d, 4);
            float a = __expf((d + du_r + svB) * scale);
            a = bvalidA ? a : 0.f;
            s_reg += a;
            t0 += a * eavB.x; t1 += a * eavB.y;
            p = __builtin_amdgcn_cvt_pk_f32_fp8(vB.x, false); va[0] += a*p.x; va[1] += a*p.y;
            p = __builtin_amdgcn_cvt_pk_f32_fp8(vB.x, true);  va[2] += a*p.x; va[3] += a*p.y;
            p = __builtin_amdgcn_cvt_pk_f32_fp8(vB.y, false); va[4] += a*p.x; va[5] += a*p.y;
            p = __builtin_amdgcn_cvt_pk_f32_fp8(vB.y, true);  va[6] += a*p.x; va[7] += a*p.y;
            p = __builtin_amdgcn_cvt_pk_f32_fp8(vB.z, false); va[8] += a*p.x; va[9] += a*p.y;
            p = __builtin_amdgcn_cvt_pk_f32_fp8(vB.z, true);  va[10] += a*p.x; va[11] += a*p.y;
            p = __builtin_amdgcn_cvt_pk_f32_fp8(vB.w, false); va[12] += a*p.x; va[13] += a*p.y;
            p = __builtin_amdgcn_cvt_pk_f32_fp8(vB.w, true);  va[14] += a*p.x; va[15] += a*p.y;
        }
        // rotate pipeline registers
        xA = xA2; xB = xB2; vA = vA2; vB = vB2;
        svA = svA2; svB = svB2; eavA = eavA2; eavB = eavB2;
        bvalidA = bvN;
    }
    // merge halves through LDS (conflict-free layout)
    if (half == 0) {
        #pragma unroll
        for (int i = 0; i < 16; ++i) lva[ns][i][lane] = va[i];
        lst[ns][0][lane] = s_reg;
        lst[ns][1][lane] = t0;
        lst[ns][2][lane] = t1;
    }
    __syncthreads();
    if (half == 1) {
        s_reg += lst[ns][0][lane];
        t0 += lst[ns][1][lane];
        t1 += lst[ns][2][lane];
        #pragma unroll
        for (int i = 0; i < 16; ++i) va[i] += lva[ns][i][lane];

        float inv = 1.f / (s_reg + 1e-16f);
        ushort2 tw;
        tw.x = f2bf(t0 * inv);
        tw.y = f2bf(t1 * inv);
        *(ushort2*)(ttb + (size_t)n * 128 + h * 16 + 2 * lh) = tw;
        float sc = inv * 0.125f;
        #pragma unroll
        for (int i = 0; i < 16; ++i) {
            float o = va[i] * sc;
            o += __shfl_xor(o, 8);
            o += __shfl_xor(o, 16);
            o += __shfl_xor(o, 32);
            va[i] = o;
        }
        if (lane < 8) {
            float* hp = hsum + (size_t)n * 128 + lane * 16;
            #pragma unroll
            for (int p2 = 0; p2 < 4; ++p2) {
                float4 h4 = make_float4(va[4 * p2], va[4 * p2 + 1],
                                        va[4 * p2 + 2], va[4 * p2 + 3]);
                ((float4*)hp)[p2] = h4;
            }
        }
    }
}

// -- out GEMM: m-tile 32 (313 blocks), LDS-staged A, epilogue + final -------
__global__ __launch_bounds__(256) void out_gemm(
    const unsigned short* __restrict__ ttb, const unsigned short* __restrict__ w2t,
    const float* __restrict__ hsum, const unsigned short* __restrict__ sqb,
    float* __restrict__ pooled, int* __restrict__ done,
    const float* __restrict__ Wd, const float* __restrict__ bd,
    float* __restrict__ out) {
    __shared__ unsigned short As[32][136];
    __shared__ float pool_sh[128];
    __shared__ int last_sh;
    int tid = threadIdx.x;
    int m0 = blockIdx.x * 32;
    int w = tid >> 6, lane = tid & 63;
    int wm = (w >> 1) * 16, wn = (w & 1) * 64;
    int quad = lane >> 4, l16 = lane & 15;
    if (tid < 128) pool_sh[tid] = 0.f;
    #pragma unroll
    for (int tI = 0; tI < 2; ++tI) {
        int cId = tid + tI * 256;
        int r = cId >> 4, c8 = (cId & 15) << 3;
        int gr = m0 + r;
        uint4 av = make_uint4(0u, 0u, 0u, 0u);
        if (gr < N_NODES)
            av = *(const uint4*)(ttb + (size_t)gr * 128 + c8);
        *(uint4*)(&As[r][c8]) = av;
    }
    __syncthreads();
    f32x4 acc[4];
    #pragma unroll
    for (int j = 0; j < 4; ++j) acc[j] = (f32x4){0.f, 0.f, 0.f, 0.f};

    const unsigned short* bb = w2t + (size_t)(wn + l16) * 128 + quad * 8;
    #pragma unroll
    for (int ks = 0; ks < 128; ks += 32) {
        bf16x8 a = *(const bf16x8*)&As[wm + l16][ks + quad * 8];
        #pragma unroll
        for (int nt = 0; nt < 4; ++nt) {
            bf16x8 b = *(const bf16x8*)(bb + (size_t)nt * 16 * 128 + ks);
            acc[nt] = __builtin_amdgcn_mfma_f32_16x16x32_bf16(a, b, acc[nt], 0, 0, 0);
        }
    }
    float pl[4] = {0.f, 0.f, 0.f, 0.f};
    #pragma unroll
    for (int r = 0; r < 4; ++r) {
        int row = m0 + wm + quad * 4 + r;
        if (row >= N_NODES) continue;
        #pragma unroll
        for (int nt = 0; nt < 4; ++nt) {
            int col = wn + nt * 16 + l16;
            float val = acc[nt][r] + hsum[(size_t)row * 128 + col]
                        + bf2f(sqb[(size_t)row * 256 + col]);
            pl[nt] += fmaxf(val, 0.f);
        }
    }
    #pragma unroll
    for (int nt = 0; nt < 4; ++nt)
        atomicAdd(&pool_sh[wn + nt * 16 + l16], pl[nt]);
    __syncthreads();
    if (tid < 128) atomAddF(&pooled[tid], pool_sh[tid]);
    __threadfence();
    if (tid == 0) last_sh = (atomicAdd(done, 1) == (int)gridDim.x - 1);
    __syncthreads();
    if (last_sh && tid < 64) {
        float p0 = __hip_atomic_load(&pooled[2 * tid], __ATOMIC_RELAXED,
                                     __HIP_MEMORY_SCOPE_AGENT);
        float p1 = __hip_atomic_load(&pooled[2 * tid + 1], __ATOMIC_RELAXED,
                                     __HIP_MEMORY_SCOPE_AGENT);
        float vv = p0 * Wd[2 * tid] + p1 * Wd[2 * tid + 1];
        vv += __shfl_xor(vv, 1);  vv += __shfl_xor(vv, 2);  vv += __shfl_xor(vv, 4);
        vv += __shfl_xor(vv, 8);  vv += __shfl_xor(vv, 16); vv += __shfl_xor(vv, 32);
        if (tid == 0) out[0] = vv + bd[0];
    }
}

extern "C" void kernel_launch(void* const* d_in, const int* in_sizes, int n_in,
                              void* d_out, int out_size, void* d_ws, size_t ws_size,
                              hipStream_t stream) {
    const float* x     = (const float*)d_in[0];
    const float* eattr = (const float*)d_in[1];
    const int*   ei    = (const int*)d_in[2];
    const float* Wq    = (const float*)d_in[3];
    const float* bq    = (const float*)d_in[4];
    const float* Wk    = (const float*)d_in[5];
    const float* bk    = (const float*)d_in[6];
    const float* Wv    = (const float*)d_in[7];
    const float* bv    = (const float*)d_in[8];
    const float* We    = (const float*)d_in[9];
    const float* Wskip = (const float*)d_in[10];
    const float* bskip = (const float*)d_in[11];
    const float* Wd    = (const float*)d_in[12];
    const float* bd    = (const float*)d_in[13];
    float* out = (float*)d_out;

    char* ws = (char*)d_ws;
    unsigned char*  xgf8 = (unsigned char*)(ws + 0);           // 10,240,000
    unsigned char*  xv   = (unsigned char*)(ws + 10240000);    // 20,480,000
    unsigned short* sqb  = (unsigned short*)(ws + 30720000);   //  5,120,000
    float* hsum = (float*)(ws + 35840000);                     //  5,120,000
    unsigned short* xb   = (unsigned short*)(ws + 40960000);   //  2,560,000
    unsigned short* ttb  = xb;  // reuse: xb dead after gemm_mfma
    float* du   = (float*)(ws + 43520000);                     //    320,000
    unsigned short* wt   = (unsigned short*)(ws + 43840000);   //    622,592
    float* bias = (float*)(ws + 44462592);                     //      9,728
    unsigned short* w2t  = (unsigned short*)(ws + 44472320);   //     32,768
    int* cnt    = (int*)(ws + 44505088);                       //     40,000
    float* pooled = (float*)(ws + 44545088);                   //        512
    int* done   = (int*)(ws + 44545600);                       //         16
    int2* slots = (int2*)(ws + 44545616);                      //  3,840,000

    hipMemsetAsync(cnt, 0, 40000 + 512 + 16, stream);

    prep_all<<<PREP_D, 256, 0, stream>>>(
        x, xb, xv, ei, cnt, slots, Wq, Wk, Wv, Wskip, We, bq, bk, bv, bskip,
        wt, bias, w2t);

    gemm_mfma<<<dim3(NB2, (N_NODES + 127) / 128), 256, 0, stream>>>(
        xb, wt, bias, xgf8, xv, sqb, du);

    node_kernel<<<N_NODES / 2, 256, 0, stream>>>(
        xgf8, xv, sqb, eattr, du, slots, cnt, ttb, hsum);

    out_gemm<<<(N_NODES + 31) / 32, 256, 0, stream>>>(
        ttb, w2t, hsum, sqb, pooled, done, Wd, bd, out);
}

// Round 18
// 200.876 us; speedup vs baseline: 1.1482x; 1.0180x over previous
//
#include <hip/hip_runtime.h>

#define N_NODES 10000
#define N_EDGES 100000
#define F_NODE 128
#define HEADS 8
#define HC 1024
#define NCOLS2 2432  // xg(1024) v(1024) skip(128) qwe(128) du(8) sv(8) pad(112)
#define NB2 (NCOLS2 / 128)   // 19
#define SLOT_CAP 48
#define XV_STRIDE 2048       // bytes: [x fp8 128][sv f32 32][pad][v fp8 @1024]

typedef __attribute__((ext_vector_type(8))) short bf16x8;
typedef __attribute__((ext_vector_type(4))) float f32x4;
typedef __attribute__((ext_vector_type(2))) float f32x2;

__device__ __forceinline__ void atomAddF(float* p, float v) {
    unsafeAtomicAdd(p, v);
}
__device__ __forceinline__ unsigned short f2bf(float f) {
    union { float f; unsigned u; } c; c.f = f;
    unsigned u = c.u + 0x7fffu + ((c.u >> 16) & 1u);  // RNE
    return (unsigned short)(u >> 16);
}
__device__ __forceinline__ float bLo(unsigned x) {
    union { unsigned u; float f; } c; c.u = x << 16; return c.f;
}
__device__ __forceinline__ float bHi(unsigned x) {
    union { unsigned u; float f; } c; c.u = x & 0xffff0000u; return c.f;
}
__device__ __forceinline__ float bf2f(unsigned short u) {
    union { unsigned u; float f; } c; c.u = ((unsigned)u) << 16; return c.f;
}
__device__ __forceinline__ unsigned pk4fp8(unsigned a, unsigned b) {
    int w = __builtin_amdgcn_cvt_pk_fp8_f32(bLo(a), bHi(a), 0, false);
    w = __builtin_amdgcn_cvt_pk_fp8_f32(bLo(b), bHi(b), w, true);
    return (unsigned)w;
}
__device__ __forceinline__ float dot128(const float* __restrict__ a,
                                        const float* __restrict__ b) {
    const float4* a4 = (const float4*)a;
    const float4* b4 = (const float4*)b;
    float s = 0.f;
    #pragma unroll
    for (int c = 0; c < 32; ++c) {
        float4 x4 = a4[c], y4 = b4[c];
        s += x4.x * y4.x + x4.y * y4.y + x4.z * y4.z + x4.w * y4.w;
    }
    return s;
}

// ====== fused prep: conv + zero-init (cnt/pooled/done) + W build ======
// Edge scatter moved to gemm_mfma (stream-ordered after this kernel).
#define PREP_A 1250
#define PREP_B (PREP_A + NCOLS2 / 2)       // 2466
#define PREP_C (PREP_B + 10)               // 2476
#define PREP_D (PREP_C + 64)               // 2540
__global__ __launch_bounds__(256) void prep_all(
    const float* __restrict__ x, unsigned short* __restrict__ xb,
    unsigned char* __restrict__ xv, int* __restrict__ cnt,
    float* __restrict__ pooled,
    const float* __restrict__ Wq, const float* __restrict__ Wk,
    const float* __restrict__ Wv, const float* __restrict__ Wskip,
    const float* __restrict__ We, const float* __restrict__ bq,
    const float* __restrict__ bk, const float* __restrict__ bv,
    const float* __restrict__ bskip, unsigned short* __restrict__ wt,
    float* __restrict__ bias, unsigned short* __restrict__ w2t) {
    int tid = threadIdx.x;
    if (blockIdx.x < PREP_A) {
        int i = blockIdx.x * 256 + tid;
        float4 f = ((const float4*)x)[i];
        ushort4 o;
        o.x = f2bf(f.x); o.y = f2bf(f.y); o.z = f2bf(f.z); o.w = f2bf(f.w);
        ((ushort4*)xb)[i] = o;
        int w = __builtin_amdgcn_cvt_pk_fp8_f32(f.x, f.y, 0, false);
        w = __builtin_amdgcn_cvt_pk_fp8_f32(f.z, f.w, w, true);
        ((unsigned*)xv)[((i >> 5) << 9) + (i & 31)] = (unsigned)w;
        // zero-init workspace accumulators (consumed by later kernels)
        if (i < N_NODES) cnt[i] = 0;
        else if (i < N_NODES + 129) pooled[i - N_NODES] = 0.f;  // pooled[128]+done
    } else if (blockIdx.x < PREP_B) {
        __shared__ float wesh[2][128];
        int bi = blockIdx.x - PREP_A;
        int cid = tid >> 7, d = tid & 127;
        int n = 2 * bi + cid;
        float val;
        if (n < 1024) {           // G_h[d,f2] = sum_c Wq[d,hc] Wk[f2,hc]
            int h = n >> 7, f2 = n & 127;
            wesh[cid][d] = Wk[(size_t)f2 * HC + h * 128 + d];
            __syncthreads();
            val = dot128(Wq + (size_t)d * HC + h * 128, wesh[cid]);
        } else if (n < 2048) {
            val = Wv[(size_t)d * HC + (n - 1024)];
        } else if (n < 2176) {
            val = Wskip[(size_t)d * 128 + (n - 2048)];
        } else if (n < 2304) {
            int hf = n - 2176, h = hf >> 4, f = hf & 15;
            wesh[cid][d] = We[(size_t)f * HC + h * 128 + d];
            __syncthreads();
            val = dot128(Wq + (size_t)d * HC + h * 128, wesh[cid]);
        } else if (n < 2312) {    // du col: Wq_h . bk_h
            int h = n - 2304;
            wesh[cid][d] = bk[h * 128 + d];
            __syncthreads();
            val = dot128(Wq + (size_t)d * HC + h * 128, wesh[cid]);
        } else if (n < 2320) {    // sv col: Wk_h . bq_h
            int h = n - 2312;
            wesh[cid][d] = bq[h * 128 + d];
            __syncthreads();
            val = dot128(Wk + (size_t)d * HC + h * 128, wesh[cid]);
        } else {
            val = 0.f;
        }
        wt[(size_t)n * 128 + d] = f2bf(val);
    } else if (blockIdx.x < PREP_C) {
        int n = (blockIdx.x - PREP_B) * 256 + tid;
        if (n >= NCOLS2) return;
        float val;
        if (n < 1024) val = 0.f;
        else if (n < 2048) val = bv[n - 1024];
        else if (n < 2176) val = bskip[n - 2048];
        else if (n < 2304) {
            int hf = n - 2176, h = hf >> 4, f = hf & 15;
            float s = 0.f;
            for (int c = 0; c < 128; ++c)
                s += bq[h * 128 + c] * We[(size_t)f * HC + h * 128 + c];
            val = s;
        } else if (n < 2312) {    // c_h = bq_h . bk_h
            int h = n - 2304;
            float s = 0.f;
            for (int c = 0; c < 128; ++c) s += bq[h * 128 + c] * bk[h * 128 + c];
            val = s;
        } else val = 0.f;
        bias[n] = val;
    } else {
        int c = (blockIdx.x - PREP_C) * 2 + (tid >> 7);
        int d = tid & 127;
        int h = d >> 4, f = d & 15;
        w2t[(size_t)c * 128 + d] = f2bf(We[(size_t)f * HC + h * 128 + c] * 0.125f);
    }
}

// ---- MFMA GEMM + edge scatter: [10000,128]bf16 x [128,2432]bf16 ----
__global__ __launch_bounds__(256) void gemm_mfma(
    const unsigned short* __restrict__ xb, const unsigned short* __restrict__ wt,
    const float* __restrict__ bias, unsigned char* __restrict__ xgf8,
    unsigned char* __restrict__ xv, unsigned short* __restrict__ sqb,
    float* __restrict__ du, const int* __restrict__ ei,
    int* __restrict__ cnt, int2* __restrict__ slots) {
    __shared__ unsigned short lds[18432];
    unsigned short (*As)[72] = (unsigned short(*)[72])lds;
    unsigned short (*Bs)[72] = (unsigned short(*)[72])(lds + 9216);
    int tid = threadIdx.x;
    int n0 = blockIdx.x * 128, m0 = blockIdx.y * 128;
    int w = tid >> 6, lane = tid & 63;
    int wm = (w >> 1) * 64, wn = (w & 1) * 64;
    int quad = lane >> 4, l16 = lane & 15;

    // edge scatter (overlaps MFMA; cnt zeroed by prep, stream-ordered)
    {
        int e = (blockIdx.y * NB2 + blockIdx.x) * 256 + tid;
        if (e < N_EDGES) {
            int src = ei[e];
            int dst = ei[N_EDGES + e];
            int pos = atomicAdd(&cnt[dst], 1);
            if (pos < SLOT_CAP) slots[(size_t)dst * SLOT_CAP + pos] = make_int2(src, e);
        }
    }

    f32x4 acc[4][4];
    #pragma unroll
    for (int i = 0; i < 4; ++i)
        #pragma unroll
        for (int j = 0; j < 4; ++j) acc[i][j] = (f32x4){0.f, 0.f, 0.f, 0.f};

    for (int ko = 0; ko < 128; ko += 64) {
        #pragma unroll
        for (int tI = 0; tI < 4; ++tI) {
            int cId = tid + tI * 256;
            int r = cId >> 3, c8 = (cId & 7) << 3;
            int gr = m0 + r;
            uint4 av = make_uint4(0u, 0u, 0u, 0u);
            if (gr < N_NODES)
                av = *(const uint4*)(xb + (size_t)gr * 128 + ko + c8);
            *(uint4*)(&As[r][c8]) = av;
            *(uint4*)(&Bs[r][c8]) =
                *(const uint4*)(wt + (size_t)(n0 + r) * 128 + ko + c8);
        }
        __syncthreads();
        #pragma unroll
        for (int ks = 0; ks < 64; ks += 32) {
            bf16x8 a[4], b[4];
            #pragma unroll
            for (int mt = 0; mt < 4; ++mt)
                a[mt] = *(const bf16x8*)&As[wm + mt * 16 + l16][ks + quad * 8];
            #pragma unroll
            for (int nt = 0; nt < 4; ++nt)
                b[nt] = *(const bf16x8*)&Bs[wn + nt * 16 + l16][ks + quad * 8];
            #pragma unroll
            for (int mt = 0; mt < 4; ++mt)
                #pragma unroll
                for (int nt = 0; nt < 4; ++nt)
                    acc[mt][nt] = __builtin_amdgcn_mfma_f32_16x16x32_bf16(
                        a[mt], b[nt], acc[mt][nt], 0, 0, 0);
        }
        __syncthreads();
    }
    int nt0 = n0 >> 7;  // 0..7 xg, 8..15 v, 16/17 sq, 18 du/sv
    if (nt0 >= 16) {
        #pragma unroll
        for (int mt = 0; mt < 4; ++mt)
            #pragma unroll
            for (int r = 0; r < 4; ++r) {
                int row = m0 + wm + mt * 16 + quad * 4 + r;
                if (row >= N_NODES) continue;
                #pragma unroll
                for (int nt = 0; nt < 4; ++nt) {
                    int col = n0 + wn + nt * 16 + l16;
                    float val = acc[mt][nt][r] + bias[col];
                    if (col < 2304) {
                        sqb[(size_t)row * 256 + (col - 2048)] = f2bf(val);
                    } else if (col < 2312) {
                        du[(size_t)row * 8 + (col - 2304)] = val;
                    } else if (col < 2320) {
                        *(float*)(xv + (size_t)row * XV_STRIDE + 128 +
                                  (col - 2312) * 4) = val;
                    }
                }
            }
    } else {
        unsigned short* wst = lds + w * 4608;
        #pragma unroll
        for (int mt = 0; mt < 4; ++mt)
            #pragma unroll
            for (int r = 0; r < 4; ++r) {
                int rl = mt * 16 + quad * 4 + r;
                #pragma unroll
                for (int nt = 0; nt < 4; ++nt) {
                    int cl = nt * 16 + l16;
                    wst[rl * 72 + cl] = f2bf(acc[mt][nt][r] + bias[n0 + wn + cl]);
                }
            }
        int colbase = (n0 & 1023) + wn;
        #pragma unroll
        for (int p = 0; p < 4; ++p) {
            int rl = p * 16 + (lane >> 2);
            int row = m0 + wm + rl;
            if (row < N_NODES) {
                const uint4* sp = (const uint4*)(wst + rl * 72 + (lane & 3) * 16);
                uint4 u0 = sp[0], u1 = sp[1];
                uint4 o;
                o.x = pk4fp8(u0.x, u0.y);
                o.y = pk4fp8(u0.z, u0.w);
                o.z = pk4fp8(u1.x, u1.y);
                o.w = pk4fp8(u1.z, u1.w);
                if (nt0 < 8) {
                    *(uint4*)(xgf8 + (size_t)row * 1024 + colbase +
                              (lane & 3) * 16) = o;
                } else {
                    *(uint4*)(xv + (size_t)row * XV_STRIDE + 1024 + colbase +
                              (lane & 3) * 16) = o;
                }
            }
        }
    }
}

// -------- node attention: TWO WAVES PER NODE, 2-edge unroll + SW pipeline --
__global__ __launch_bounds__(256) void node_kernel(
    const unsigned char* __restrict__ xgf8, const unsigned char* __restrict__ xv,
    const unsigned short* __restrict__ sqb, const float* __restrict__ ea,
    const float* __restrict__ du, const int2* __restrict__ slots,
    const int* __restrict__ cnt, unsigned short* __restrict__ ttb,
    float* __restrict__ hsum) {
    __shared__ float lva[2][16][64];   // [ns][i][lane] -> conflict-free
    __shared__ float lst[2][3][64];    // s, t0, t1
    int t = threadIdx.x;
    int w = t >> 6, lane = t & 63;
    int ns = w >> 1;          // node slot in block (0/1)
    int half = w & 1;
    int lh = lane & 7, h = lane >> 3;
    const float scale = 0.08838834764831845f;  // 1/sqrt(128)
    int n = blockIdx.x * 2 + ns;   // grid = 5000 exactly

    uint4 gq = *(const uint4*)(xgf8 + (size_t)n * 1024 + 16 * lane);
    float gf[16];
    {
        f32x2 p;
        p = __builtin_amdgcn_cvt_pk_f32_fp8(gq.x, false); gf[0] = p.x; gf[1] = p.y;
        p = __builtin_amdgcn_cvt_pk_f32_fp8(gq.x, true);  gf[2] = p.x; gf[3] = p.y;
        p = __builtin_amdgcn_cvt_pk_f32_fp8(gq.y, false); gf[4] = p.x; gf[5] = p.y;
        p = __builtin_amdgcn_cvt_pk_f32_fp8(gq.y, true);  gf[6] = p.x; gf[7] = p.y;
        p = __builtin_amdgcn_cvt_pk_f32_fp8(gq.z, false); gf[8] = p.x; gf[9] = p.y;
        p = __builtin_amdgcn_cvt_pk_f32_fp8(gq.z, true);  gf[10] = p.x; gf[11] = p.y;
        p = __builtin_amdgcn_cvt_pk_f32_fp8(gq.w, false); gf[12] = p.x; gf[13] = p.y;
        p = __builtin_amdgcn_cvt_pk_f32_fp8(gq.w, true);  gf[14] = p.x; gf[15] = p.y;
    }
    ushort2 qwu = *(const ushort2*)(sqb + (size_t)n * 256 + 128 + h * 16 + 2 * lh);
    float qwx = bf2f(qwu.x), qwy = bf2f(qwu.y);
    float du_r = du[(size_t)n * 8 + h];

    int cn = cnt[n];
    cn = (cn > SLOT_CAP) ? SLOT_CAP : cn;
    int mid = (cn + 1) >> 1;
    int begin = half ? mid : 0;
    int end = half ? cn : mid;
    const int2* sp = slots + (size_t)n * SLOT_CAP;
    float va[16];
    #pragma unroll
    for (int i = 0; i < 16; ++i) va[i] = 0.f;
    float s_reg = 0.f, t0 = 0.f, t1 = 0.f;

    // ---- software pipeline: prefetch group (slots + gathers) ----
    uint4 xA, xB, vA, vB;
    float svA, svB;
    float2 eavA, eavB;
    bool bvalidA = false;
    if (begin < end) {
        bool bv0 = (begin + 1 < end);
        int i1 = bv0 ? begin + 1 : begin;
        int2 sa = sp[begin], sb = sp[i1];
        const unsigned char* baseA = xv + ((size_t)sa.x << 11);
        const unsigned char* baseB = xv + ((size_t)sb.x << 11);
        xA = *(const uint4*)(baseA + lh * 16);
        xB = *(const uint4*)(baseB + lh * 16);
        vA = *(const uint4*)(baseA + 1024 + lane * 16);
        vB = *(const uint4*)(baseB + 1024 + lane * 16);
        svA = *(const float*)(baseA + 128 + h * 4);
        svB = *(const float*)(baseB + 128 + h * 4);
        eavA = *(const float2*)(ea + (size_t)sa.y * 16 + 2 * lh);
        eavB = *(const float2*)(ea + (size_t)sb.y * 16 + 2 * lh);
        bvalidA = bv0;
    }

    for (int ii = begin; ii < end; ii += 2) {
        int nx = (ii + 2 < end) ? ii + 2 : ii;
        bool bvN = (nx + 1 < end);
        int n1 = bvN ? nx + 1 : nx;
        int2 sa2 = sp[nx], sb2 = sp[n1];
        const unsigned char* baseA2 = xv + ((size_t)sa2.x << 11);
        const unsigned char* baseB2 = xv + ((size_t)sb2.x << 11);
        uint4 xA2 = *(const uint4*)(baseA2 + lh * 16);
        uint4 xB2 = *(const uint4*)(baseB2 + lh * 16);
        uint4 vA2 = *(const uint4*)(baseA2 + 1024 + lane * 16);
        uint4 vB2 = *(const uint4*)(baseB2 + 1024 + lane * 16);
        float svA2 = *(const float*)(baseA2 + 128 + h * 4);
        float svB2 = *(const float*)(baseB2 + 128 + h * 4);
        float2 eavA2 = *(const float2*)(ea + (size_t)sa2.y * 16 + 2 * lh);
        float2 eavB2 = *(const float2*)(ea + (size_t)sb2.y * 16 + 2 * lh);

        // ----- edge A -----
        {
            float d = eavA.x * qwx + eavA.y * qwy;
            f32x2 p;
            p = __builtin_amdgcn_cvt_pk_f32_fp8(xA.x, false); d += gf[0]*p.x + gf[1]*p.y;
            p = __builtin_amdgcn_cvt_pk_f32_fp8(xA.x, true);  d += gf[2]*p.x + gf[3]*p.y;
            p = __builtin_amdgcn_cvt_pk_f32_fp8(xA.y, false); d += gf[4]*p.x + gf[5]*p.y;
            p = __builtin_amdgcn_cvt_pk_f32_fp8(xA.y, true);  d += gf[6]*p.x + gf[7]*p.y;
            p = __builtin_amdgcn_cvt_pk_f32_fp8(xA.z, false); d += gf[8]*p.x + gf[9]*p.y;
            p = __builtin_amdgcn_cvt_pk_f32_fp8(xA.z, true);  d += gf[10]*p.x + gf[11]*p.y;
            p = __builtin_amdgcn_cvt_pk_f32_fp8(xA.w, false); d += gf[12]*p.x + gf[13]*p.y;
            p = __builtin_amdgcn_cvt_pk_f32_fp8(xA.w, true);  d += gf[14]*p.x + gf[15]*p.y;
            d += __shfl_xor(d, 1); d += __shfl_xor(d, 2); d += __shfl_xor(d, 4);
            float a = __expf((d + du_r + svA) * scale);
            s_reg += a;
            t0 += a * eavA.x; t1 += a * eavA.y;
            p = __builtin_amdgcn_cvt_pk_f32_fp8(vA.x, false); va[0] += a*p.x; va[1] += a*p.y;
            p = __builtin_amdgcn_cvt_pk_f32_fp8(vA.x, true);  va[2] += a*p.x; va[3] += a*p.y;
            p = __builtin_amdgcn_cvt_pk_f32_fp8(vA.y, false); va[4] += a*p.x; va[5] += a*p.y;
            p = __builtin_amdgcn_cvt_pk_f32_fp8(vA.y, true);  va[6] += a*p.x; va[7] += a*p.y;
            p = __builtin_amdgcn_cvt_pk_f32_fp8(vA.z, false); va[8] += a*p.x; va[9] += a*p.y;
            p = __builtin_amdgcn_cvt_pk_f32_fp8(vA.z, true);  va[10] += a*p.x; va[11] += a*p.y;
            p = __builtin_amdgcn_cvt_pk_f32_fp8(vA.w, false); va[12] += a*p.x; va[13] += a*p.y;
            p = __builtin_amdgcn_cvt_pk_f32_fp8(vA.w, true);  va[14] += a*p.x; va[15] += a*p.y;
        }
        // ----- edge B (masked if duplicate) -----
        {
            float d = eavB.x * qwx + eavB.y * qwy;
            f32x2 p;
            p = __builtin_amdgcn_cvt_pk_f32_fp8(xB.x, false); d += gf[0]*p.x + gf[1]*p.y;
            p = __builtin_amdgcn_cvt_pk_f32_fp8(xB.x, true);  d += gf[2]*p.x + gf[3]*p.y;
            p = __builtin_amdgcn_cvt_pk_f32_fp8(xB.y, false); d += gf[4]*p.x + gf[5]*p.y;
            p = __builtin_amdgcn_cvt_pk_f32_fp8(xB.y, true);  d += gf[6]*p.x + gf[7]*p.y;
            p = __builtin_amdgcn_cvt_pk_f32_fp8(xB.z, false); d += gf[8]*p.x + gf[9]*p.y;
            p = __builtin_amdgcn_cvt_pk_f32_fp8(xB.z, true);  d += gf[10]*p.x + gf[11]*p.y;
            p = __builtin_amdgcn_cvt_pk_f32_fp8(xB.w, false); d += gf[12]*p.x + gf[13]*p.y;
            p = __builtin_amdgcn_cvt_pk_f32_fp8(xB.w, true);  d += gf[14]*p.x + gf[15]*p.y;
            d += __shfl_xor(d, 1); d += __shfl_xor(d, 2); d += __shfl_xor(d, 4);
            float a = __expf((d + du_r + svB) * scale);
            a = bvalidA ? a : 0.f;
            s_reg += a;
            t0 += a * eavB.x; t1 += a * eavB.y;
            p = __builtin_amdgcn_cvt_pk_f32_fp8(vB.x, false); va[0] += a*p.x; va[1] += a*p.y;
            p = __builtin_amdgcn_cvt_pk_f32_fp8(vB.x, true);  va[2] += a*p.x; va[3] += a*p.y;
            p = __builtin_amdgcn_cvt_pk_f32_fp8(vB.y, false); va[4] += a*p.x; va[5] += a*p.y;
            p = __builtin_amdgcn_cvt_pk_f32_fp8(vB.y, true);  va[6] += a*p.x; va[7] += a*p.y;
            p = __builtin_amdgcn_cvt_pk_f32_fp8(vB.z, false); va[8] += a*p.x; va[9] += a*p.y;
            p = __builtin_amdgcn_cvt_pk_f32_fp8(vB.z, true);  va[10] += a*p.x; va[11] += a*p.y;
            p = __builtin_amdgcn_cvt_pk_f32_fp8(vB.w, false); va[12] += a*p.x; va[13] += a*p.y;
            p = __builtin_amdgcn_cvt_pk_f32_fp8(vB.w, true);  va[14] += a*p.x; va[15] += a*p.y;
        }
        xA = xA2; xB = xB2; vA = vA2; vB = vB2;
        svA = svA2; svB = svB2; eavA = eavA2; eavB = eavB2;
        bvalidA = bvN;
    }
    // merge halves through LDS (conflict-free layout)
    if (half == 0) {
        #pragma unroll
        for (int i = 0; i < 16; ++i) lva[ns][i][lane] = va[i];
        lst[ns][0][lane] = s_reg;
        lst[ns][1][lane] = t0;
        lst[ns][2][lane] = t1;
    }
    __syncthreads();
    if (half == 1) {
        s_reg += lst[ns][0][lane];
        t0 += lst[ns][1][lane];
        t1 += lst[ns][2][lane];
        #pragma unroll
        for (int i = 0; i < 16; ++i) va[i] += lva[ns][i][lane];

        float inv = 1.f / (s_reg + 1e-16f);
        ushort2 tw;
        tw.x = f2bf(t0 * inv);
        tw.y = f2bf(t1 * inv);
        *(ushort2*)(ttb + (size_t)n * 128 + h * 16 + 2 * lh) = tw;
        float sc = inv * 0.125f;
        #pragma unroll
        for (int i = 0; i < 16; ++i) {
            float o = va[i] * sc;
            o += __shfl_xor(o, 8);
            o += __shfl_xor(o, 16);
            o += __shfl_xor(o, 32);
            va[i] = o;
        }
        if (lane < 8) {
            float* hp = hsum + (size_t)n * 128 + lane * 16;
            #pragma unroll
            for (int p2 = 0; p2 < 4; ++p2) {
                float4 h4 = make_float4(va[4 * p2], va[4 * p2 + 1],
                                        va[4 * p2 + 2], va[4 * p2 + 3]);
                ((float4*)hp)[p2] = h4;
            }
        }
    }
}

// -- out GEMM: m-tile 32 (313 blocks), LDS-staged A, epilogue + final -------
__global__ __launch_bounds__(256) void out_gemm(
    const unsigned short* __restrict__ ttb, const unsigned short* __restrict__ w2t,
    const float* __restrict__ hsum, const unsigned short* __restrict__ sqb,
    float* __restrict__ pooled, int* __restrict__ done,
    const float* __restrict__ Wd, const float* __restrict__ bd,
    float* __restrict__ out) {
    __shared__ unsigned short As[32][136];
    __shared__ float pool_sh[128];
    __shared__ int last_sh;
    int tid = threadIdx.x;
    int m0 = blockIdx.x * 32;
    int w = tid >> 6, lane = tid & 63;
    int wm = (w >> 1) * 16, wn = (w & 1) * 64;
    int quad = lane >> 4, l16 = lane & 15;
    if (tid < 128) pool_sh[tid] = 0.f;
    #pragma unroll
    for (int tI = 0; tI < 2; ++tI) {
        int cId = tid + tI * 256;
        int r = cId >> 4, c8 = (cId & 15) << 3;
        int gr = m0 + r;
        uint4 av = make_uint4(0u, 0u, 0u, 0u);
        if (gr < N_NODES)
            av = *(const uint4*)(ttb + (size_t)gr * 128 + c8);
        *(uint4*)(&As[r][c8]) = av;
    }
    __syncthreads();
    f32x4 acc[4];
    #pragma unroll
    for (int j = 0; j < 4; ++j) acc[j] = (f32x4){0.f, 0.f, 0.f, 0.f};

    const unsigned short* bb = w2t + (size_t)(wn + l16) * 128 + quad * 8;
    #pragma unroll
    for (int ks = 0; ks < 128; ks += 32) {
        bf16x8 a = *(const bf16x8*)&As[wm + l16][ks + quad * 8];
        #pragma unroll
        for (int nt = 0; nt < 4; ++nt) {
            bf16x8 b = *(const bf16x8*)(bb + (size_t)nt * 16 * 128 + ks);
            acc[nt] = __builtin_amdgcn_mfma_f32_16x16x32_bf16(a, b, acc[nt], 0, 0, 0);
        }
    }
    float pl[4] = {0.f, 0.f, 0.f, 0.f};
    #pragma unroll
    for (int r = 0; r < 4; ++r) {
        int row = m0 + wm + quad * 4 + r;
        if (row >= N_NODES) continue;
        #pragma unroll
        for (int nt = 0; nt < 4; ++nt) {
            int col = wn + nt * 16 + l16;
            float val = acc[nt][r] + hsum[(size_t)row * 128 + col]
                        + bf2f(sqb[(size_t)row * 256 + col]);
            pl[nt] += fmaxf(val, 0.f);
        }
    }
    #pragma unroll
    for (int nt = 0; nt < 4; ++nt)
        atomicAdd(&pool_sh[wn + nt * 16 + l16], pl[nt]);
    __syncthreads();
    if (tid < 128) atomAddF(&pooled[tid], pool_sh[tid]);
    __threadfence();
    if (tid == 0) last_sh = (atomicAdd(done, 1) == (int)gridDim.x - 1);
    __syncthreads();
    if (last_sh && tid < 64) {
        float p0 = __hip_atomic_load(&pooled[2 * tid], __ATOMIC_RELAXED,
                                     __HIP_MEMORY_SCOPE_AGENT);
        float p1 = __hip_atomic_load(&pooled[2 * tid + 1], __ATOMIC_RELAXED,
                                     __HIP_MEMORY_SCOPE_AGENT);
        float vv = p0 * Wd[2 * tid] + p1 * Wd[2 * tid + 1];
        vv += __shfl_xor(vv, 1);  vv += __shfl_xor(vv, 2);  vv += __shfl_xor(vv, 4);
        vv += __shfl_xor(vv, 8);  vv += __shfl_xor(vv, 16); vv += __shfl_xor(vv, 32);
        if (tid == 0) out[0] = vv + bd[0];
    }
}

extern "C" void kernel_launch(void* const* d_in, const int* in_sizes, int n_in,
                              void* d_out, int out_size, void* d_ws, size_t ws_size,
                              hipStream_t stream) {
    const float* x     = (const float*)d_in[0];
    const float* eattr = (const float*)d_in[1];
    const int*   ei    = (const int*)d_in[2];
    const float* Wq    = (const float*)d_in[3];
    const float* bq    = (const float*)d_in[4];
    const float* Wk    = (const float*)d_in[5];
    const float* bk    = (const float*)d_in[6];
    const float* Wv    = (const float*)d_in[7];
    const float* bv    = (const float*)d_in[8];
    const float* We    = (const float*)d_in[9];
    const float* Wskip = (const float*)d_in[10];
    const float* bskip = (const float*)d_in[11];
    const float* Wd    = (const float*)d_in[12];
    const float* bd    = (const float*)d_in[13];
    float* out = (float*)d_out;

    char* ws = (char*)d_ws;
    unsigned char*  xgf8 = (unsigned char*)(ws + 0);           // 10,240,000
    unsigned char*  xv   = (unsigned char*)(ws + 10240000);    // 20,480,000
    unsigned short* sqb  = (unsigned short*)(ws + 30720000);   //  5,120,000
    float* hsum = (float*)(ws + 35840000);                     //  5,120,000
    unsigned short* xb   = (unsigned short*)(ws + 40960000);   //  2,560,000
    unsigned short* ttb  = xb;  // reuse: xb dead after gemm_mfma
    float* du   = (float*)(ws + 43520000);                     //    320,000
    unsigned short* wt   = (unsigned short*)(ws + 43840000);   //    622,592
    float* bias = (float*)(ws + 44462592);                     //      9,728
    unsigned short* w2t  = (unsigned short*)(ws + 44472320);   //     32,768
    int* cnt    = (int*)(ws + 44505088);                       //     40,000
    float* pooled = (float*)(ws + 44545088);                   //        512
    int* done   = (int*)(ws + 44545600);                       //         16
    int2* slots = (int2*)(ws + 44545616);                      //  3,840,000

    prep_all<<<PREP_D, 256, 0, stream>>>(
        x, xb, xv, cnt, pooled, Wq, Wk, Wv, Wskip, We, bq, bk, bv, bskip,
        wt, bias, w2t);

    gemm_mfma<<<dim3(NB2, (N_NODES + 127) / 128), 256, 0, stream>>>(
        xb, wt, bias, xgf8, xv, sqb, du, ei, cnt, slots);

    node_kernel<<<N_NODES / 2, 256, 0, stream>>>(
        xgf8, xv, sqb, eattr, du, slots, cnt, ttb, hsum);

    out_gemm<<<(N_NODES + 31) / 32, 256, 0, stream>>>(
        ttb, w2t, hsum, sqb, pooled, done, Wd, bd, out);
}